// Round 15
// baseline (191.793 us; speedup 1.0000x reference)
//
#include <hip/hip_runtime.h>
#include <hip/hip_bf16.h>
#include <math.h>

#define CDIM 192
#define NHEADS 6
#define WIN 7
#define KWIN 49
#define BATCH 4
#define PIX 3136      // 56*56
#define NPIX 12544    // BATCH*PIX
#define NIMG 24       // BATCH*NHEADS
#define EPSV 1e-5f

typedef __bf16 bf16x8 __attribute__((ext_vector_type(8)));
typedef float f32x16 __attribute__((ext_vector_type(16)));
typedef unsigned int uint4v __attribute__((ext_vector_type(4)));
typedef unsigned int uint2v __attribute__((ext_vector_type(2)));
typedef int int4x __attribute__((ext_vector_type(4)));
typedef int int8x __attribute__((ext_vector_type(8)));
typedef unsigned short u16;
typedef unsigned char u8;

__device__ inline u8 f32_to_fp8(float v) {
  return (u8)(__builtin_amdgcn_cvt_pk_fp8_f32(v, 0.f, 0, false) & 0xFF);
}

// 8 bf16 (as uint4v) -> 8 fp8 bytes (uint2v)
__device__ inline uint2v bf8_to_fp8x8(uint4v v) {
  const u16* h = (const u16*)&v;
  float f[8];
#pragma unroll
  for (int e = 0; e < 8; e++) {
    unsigned u = ((unsigned)h[e]) << 16;
    f[e] = __builtin_bit_cast(float, u);
  }
  int lo = __builtin_amdgcn_cvt_pk_fp8_f32(f[0], f[1], 0, false);
  lo = __builtin_amdgcn_cvt_pk_fp8_f32(f[2], f[3], lo, true);
  int hi = __builtin_amdgcn_cvt_pk_fp8_f32(f[4], f[5], 0, false);
  hi = __builtin_amdgcn_cvt_pk_fp8_f32(f[6], f[7], hi, true);
  uint2v r = {(unsigned)lo, (unsigned)hi};
  return r;
}

// ---------------- BN stats ---------------------------------------------------
__global__ __launch_bounds__(256) void bn_stats_k(const float* __restrict__ x,
                                                  float* __restrict__ stats) {
  int c = blockIdx.x;
  float s = 0.f, q = 0.f;
  for (int n = threadIdx.x; n < BATCH * PIX; n += 256) {
    int b = n / PIX, p = n - b * PIX;
    float v = x[((size_t)b * CDIM + c) * PIX + p];
    s += v; q += v * v;
  }
  __shared__ float rs[256], rq[256];
  rs[threadIdx.x] = s; rq[threadIdx.x] = q;
  __syncthreads();
  for (int st = 128; st > 0; st >>= 1) {
    if (threadIdx.x < st) { rs[threadIdx.x] += rs[threadIdx.x + st]; rq[threadIdx.x] += rq[threadIdx.x + st]; }
    __syncthreads();
  }
  if (threadIdx.x == 0) {
    float mean = rs[0] / (float)(BATCH * PIX);
    float var = rq[0] / (float)(BATCH * PIX) - mean * mean;
    stats[c] = mean;
    stats[CDIM + c] = rsqrtf(var + EPSV);
  }
}

// ------- fold BN + q-scale into qkv weights, writing fp8 K=64 frags ---------
// byte idx = (((o>>5)*3 + (c>>6))*64 + ((c>>5)&1)*32 + (o&31))*32 + (c&31)
__global__ __launch_bounds__(192) void fold_pack_k(
    const float* __restrict__ qkv_w, const float* __restrict__ qkv_b,
    const float* __restrict__ gamma, const float* __restrict__ beta,
    const float* __restrict__ stats, u8* __restrict__ pk_qkv8,
    float* __restrict__ b_eff) {
  int o = blockIdx.x, c = threadIdx.x;
  float alpha = gamma[c] * stats[CDIM + c];
  float shift = beta[c] - stats[c] * alpha;
  float w = qkv_w[o * CDIM + c];
  float scale = (o < CDIM) ? 0.17677669529663687f : 1.f;
  int bidx = (((o >> 5) * 3 + (c >> 6)) * 64 + (((c >> 5) & 1) * 32 + (o & 31))) * 32 + (c & 31);
  pk_qkv8[bidx] = f32_to_fp8(w * alpha * scale);
  __shared__ float r[CDIM];
  r[c] = w * shift;
  __syncthreads();
  if (c == 0) {
    float s = 0.f;
    for (int i = 0; i < CDIM; i++) s += r[i];
    b_eff[o] = (qkv_b[o] + s) * scale;
  }
}

// -------- fp8 K=64 frag pack: W[Cout][Cin] -> [oT][kc][lane][32B] -----------
__device__ inline void pack8_one(const float* __restrict__ W, u8* __restrict__ out,
                                 int Cin, int t, int total) {
  if (t >= total) return;
  int lane = t & 63, rest = t >> 6;
  int nKC = Cin >> 6;
  int kc = rest % nKC, oT = rest / nKC;
  int o = oT * 32 + (lane & 31), c = kc * 64 + (lane >> 5) * 32;
  const float* src = W + (size_t)o * Cin + c;
  u8 tmp[32];
#pragma unroll
  for (int e = 0; e < 32; e++) tmp[e] = f32_to_fp8(src[e]);
  *(uint4v*)(out + (size_t)t * 32) = *(uint4v*)tmp;
  *(uint4v*)(out + (size_t)t * 32 + 16) = *(uint4v*)(tmp + 16);
}

// --- merged prep: dm_w K=64 fp8 pack + proj/c1/c2 fp8 packs -----------------
__global__ __launch_bounds__(256) void prep3_k(
    const float* __restrict__ dm_w, u8* __restrict__ wTs8,
    const float* __restrict__ proj_w, u8* __restrict__ pk_proj8,
    const float* __restrict__ c1_w, u8* __restrict__ pk_c18,
    const float* __restrict__ c2_w, u8* __restrict__ pk_c28) {
  int bid = blockIdx.x, tid = threadIdx.x;
  if (bid < 784) {
    int idx = bid * 256 + tid;          // < 200704
    int e = idx & 31;
    int tmp = idx >> 5;
    int lane = tmp & 63; tmp >>= 6;
    int Mt = tmp & 1;
    int tap = tmp >> 1;                 // 0..48
    int ko = Mt * 32 + (lane & 31);
    int ci = (lane >> 5) * 32 + e;
    float v = (ko < KWIN) ? dm_w[(size_t)ko * 3136 + ci * 49 + tap] : 0.f;
    wTs8[idx] = f32_to_fp8(v);
  } else if (bid < 789) {
    pack8_one(proj_w, pk_proj8, 192, (bid - 784) * 256 + tid, 1152);
  } else if (bid < 807) {
    pack8_one(c1_w, pk_c18, 192, (bid - 789) * 256 + tid, 4608);
  } else {
    pack8_one(c2_w, pk_c28, 768, (bid - 807) * 256 + tid, 4608);
  }
}

// ---------------- MX-fp8 MFMA GEMM (256px tile, K=64 chunks) ----------------
// Per chunk per wave: 4 x mfma_scale_f32_32x32x64 (scales=1.0) + 4 B ds_reads
// + 4 A ds_reads. B staged fp8 [px][64B] slot^(px&3) swizzle; A staged 4KB.
#define MG_QKV 0
#define MG_PROJ 1
#define MG_GELU 2
#define MG_C2 3
#define MGS 2056

template <int EPI>
__global__ __launch_bounds__(256, 3) void mgemm_k(
    const u16* __restrict__ Bm, const u8* __restrict__ Apk8,
    const float* __restrict__ bias,
    float* __restrict__ outF, u16* __restrict__ outT, u16* __restrict__ outT2,
    u8* __restrict__ outQK8,
    const float* __restrict__ extra, int Cin) {
  __shared__ __align__(16) u16 BsU[8 * MGS];  // 32.9 KB (fp8 stage + epi scratch)
  __shared__ __align__(16) u8 As8[4096];      // 4 KB: [mt][lane][32B]
  u8* Bs8 = (u8*)BsU;                         // [256 px][64 B]
  int tid = threadIdx.x;
  int lane = tid & 63, wid = tid >> 6;
  int hi = lane >> 5, ln31 = lane & 31;
  int p0 = blockIdx.x * 256;
  int o0 = blockIdx.y * 64;
  int nKC = Cin >> 6;
  f32x16 acc[2][2];
#pragma unroll
  for (int mt = 0; mt < 2; mt++)
#pragma unroll
    for (int nt = 0; nt < 2; nt++)
#pragma unroll
      for (int i = 0; i < 16; i++) acc[mt][nt][i] = 0.f;

  unsigned gp_s = p0 + tid;
  unsigned bb_s = gp_s / PIX, pp_s = gp_s - bb_s * PIX;

  for (int kc = 0; kc < nKC; kc++) {
    int cc = kc * 64;
    if (EPI == MG_QKV) {
      // direct fp32 x -> fp8 staging (transpose in flight); px = tid
#pragma unroll
      for (int slot = 0; slot < 4; slot++) {
        const float* xb = extra + ((size_t)bb_s * CDIM + cc + slot * 16) * PIX + pp_s;
        u8 tmp[16];
#pragma unroll
        for (int e = 0; e < 16; e++) tmp[e] = f32_to_fp8(xb[(size_t)e * PIX]);
        *(uint4v*)&Bs8[tid * 64 + ((slot ^ (tid & 3)) << 4)] = *(uint4v*)tmp;
      }
    } else {
      // bf16 pixel-major input -> fp8 staging
#pragma unroll
      for (int i = 0; i < 4; i++) {
        int idx = i * 256 + tid;
        int px = idx >> 2, slot = idx & 3;
        const u16* src = Bm + (size_t)(p0 + px) * Cin + cc + slot * 16;
        uint2v lo = bf8_to_fp8x8(*(const uint4v*)src);
        uint2v hh = bf8_to_fp8x8(*(const uint4v*)(src + 8));
        uint4v w = {lo[0], lo[1], hh[0], hh[1]};
        *(uint4v*)&Bs8[px * 64 + ((slot ^ (px & 3)) << 4)] = w;
      }
    }
    // stage A chunk: 2 mt frags x 64 lanes x 32B = 4KB
    {
      int mt = tid >> 7, off = (tid & 127) * 16;
      const u8* src = Apk8 + (size_t)(((o0 >> 5) + mt) * nKC + kc) * 2048 + off;
      *(uint4v*)&As8[mt * 2048 + off] = *(const uint4v*)src;
    }
    __syncthreads();
    int4x a0lo = *(const int4x*)&As8[lane * 32];
    int4x a0hi = *(const int4x*)&As8[lane * 32 + 16];
    int4x a1lo = *(const int4x*)&As8[2048 + lane * 32];
    int4x a1hi = *(const int4x*)&As8[2048 + lane * 32 + 16];
    int8x a0 = __builtin_shufflevector(a0lo, a0hi, 0, 1, 2, 3, 4, 5, 6, 7);
    int8x a1 = __builtin_shufflevector(a1lo, a1hi, 0, 1, 2, 3, 4, 5, 6, 7);
#pragma unroll
    for (int nt = 0; nt < 2; nt++) {
      int px = wid * 64 + nt * 32 + ln31;
      int sw = px & 3;
      int4x blo = *(const int4x*)&Bs8[px * 64 + (((2 * hi) ^ sw) << 4)];
      int4x bhi = *(const int4x*)&Bs8[px * 64 + (((2 * hi + 1) ^ sw) << 4)];
      int8x b = __builtin_shufflevector(blo, bhi, 0, 1, 2, 3, 4, 5, 6, 7);
      acc[0][nt] = __builtin_amdgcn_mfma_scale_f32_32x32x64_f8f6f4(
          a0, b, acc[0][nt], 0, 0, 0, 127, 0, 127);
      acc[1][nt] = __builtin_amdgcn_mfma_scale_f32_32x32x64_f8f6f4(
          a1, b, acc[1][nt], 0, 0, 0, 127, 0, 127);
    }
    __syncthreads();
  }

  // ---- epilogue (unchanged layouts) ----
  if (EPI == MG_C2) {
#pragma unroll
    for (int mt = 0; mt < 2; mt++)
#pragma unroll
      for (int r = 0; r < 16; r++) {
        int o = o0 + mt * 32 + (r & 3) + 8 * (r >> 2) + 4 * hi;
        float bv = bias[o];
#pragma unroll
        for (int nt = 0; nt < 2; nt++) {
          unsigned gp = p0 + wid * 64 + nt * 32 + ln31;
          unsigned bb = gp / PIX, pp = gp - bb * PIX;
          size_t oi = ((size_t)bb * CDIM + o) * PIX + pp;
          outF[oi] = acc[mt][nt][r] + bv + extra[oi];
        }
      }
  } else {
#pragma unroll
    for (int mt = 0; mt < 2; mt++)
#pragma unroll
      for (int r = 0; r < 16; r++) {
        int o_loc = mt * 32 + (r & 3) + 8 * (r >> 2) + 4 * hi;
        int o = o0 + o_loc;
        float bv = bias[o];
#pragma unroll
        for (int nt = 0; nt < 2; nt++) {
          int p_loc = wid * 64 + nt * 32 + ln31;
          float val = acc[mt][nt][r] + bv;
          if (EPI == MG_PROJ) {
            unsigned gp = p0 + p_loc;
            unsigned bb = gp / PIX, pp = gp - bb * PIX;
            size_t oi = ((size_t)bb * CDIM + o) * PIX + pp;
            val += extra[oi];
            outF[oi] = val;
          }
          if (EPI == MG_GELU)
            val = 0.5f * val * (1.f + erff(val * 0.70710678118654752f));
          *(__hip_bfloat16*)&BsU[p_loc * 64 + (((o_loc >> 3) ^ (p_loc & 7)) << 3) + (o_loc & 7)] =
              __float2bfloat16(val);
        }
      }
    __syncthreads();
    int prow = wid * 64 + lane;
    int psw = prow & 7;
    uint4v r8[8];
#pragma unroll
    for (int g = 0; g < 8; g++)
      r8[g] = *(const uint4v*)&BsU[prow * 64 + ((g ^ psw) << 3)];
    unsigned gp = p0 + prow;
    if (EPI == MG_QKV) {
      unsigned bb = gp / PIX, pp = gp - bb * PIX;
      int s = o0 / 192;               // 0=q, 1=k, 2=v
      int rr = o0 - s * 192;
      int h0 = rr >> 5;
      if (s < 2) {
        uint2v c0 = bf8_to_fp8x8(r8[0]), c1 = bf8_to_fp8x8(r8[1]);
        uint2v c2 = bf8_to_fp8x8(r8[2]), c3 = bf8_to_fp8x8(r8[3]);
        uint2v c4 = bf8_to_fp8x8(r8[4]), c5 = bf8_to_fp8x8(r8[5]);
        uint2v c6 = bf8_to_fp8x8(r8[6]), c7 = bf8_to_fp8x8(r8[7]);
        uint4v w0 = {c0[0], c0[1], c1[0], c1[1]};
        uint4v w1 = {c2[0], c2[1], c3[0], c3[1]};
        uint4v w2 = {c4[0], c4[1], c5[0], c5[1]};
        uint4v w3 = {c6[0], c6[1], c7[0], c7[1]};
        u8* d0 = outQK8 + ((size_t)(bb * NHEADS + h0) * PIX + pp) * 64 + s * 32;
        u8* d1 = outQK8 + ((size_t)(bb * NHEADS + h0 + 1) * PIX + pp) * 64 + s * 32;
        *(uint4v*)(d0) = w0; *(uint4v*)(d0 + 16) = w1;
        *(uint4v*)(d1) = w2; *(uint4v*)(d1 + 16) = w3;
      } else {                        // v -> vT[img][pix][32] bf16
        u16* d0 = outT2 + ((size_t)(bb * NHEADS + h0) * PIX + pp) * 32;
        u16* d1 = outT2 + ((size_t)(bb * NHEADS + h0 + 1) * PIX + pp) * 32;
        *(uint4v*)(d0) = r8[0]; *(uint4v*)(d0 + 8) = r8[1];
        *(uint4v*)(d0 + 16) = r8[2]; *(uint4v*)(d0 + 24) = r8[3];
        *(uint4v*)(d1) = r8[4]; *(uint4v*)(d1 + 8) = r8[5];
        *(uint4v*)(d1 + 16) = r8[6]; *(uint4v*)(d1 + 24) = r8[7];
      }
    } else if (EPI == MG_PROJ) {
      u16* d = outT + (size_t)gp * CDIM + o0;
#pragma unroll
      for (int g = 0; g < 8; g++) *(uint4v*)(d + g * 8) = r8[g];
    } else {  // GELU -> hT [gp][768]
      u16* d = outT + (size_t)gp * 768 + o0;
#pragma unroll
      for (int g = 0; g < 8; g++) *(uint4v*)(d + g * 8) = r8[g];
    }
  }
}

// ------ 7x7 attn conv (MX-scaled fp8 K=64 MFMA) + fused softmax/PV ----------
#define VPS 40
#define SMS 65
#define DIV7(t) (((t) * 9363) >> 16)
#define LPOF(t) ((t) + 7 * DIV7(t))

__global__ __launch_bounds__(256, 4) void attn_fused_k(
    const u8* __restrict__ qk8, const u8* __restrict__ wTs8,
    const u16* __restrict__ vT,
    const float* __restrict__ dm_b, const float* __restrict__ rel_bias,
    u16* __restrict__ attnoT) {
  __shared__ __align__(16) u16 shraw[14216];   // 28432 B
  u8* patchB = (u8*)shraw;                     // phase1: 196 x 64B = 12.5 KB
  int img = blockIdx.x / 49;
  int tile = blockIdx.x % 49;
  int y0 = (tile / 7) * 8, x0 = (tile % 7) * 8;
  int tid = threadIdx.x;
  const u8* qimg = qk8 + (size_t)img * PIX * 64;
  for (int idx = tid; idx < 784; idx += 256) {
    int lp = idx >> 2, slot = idx & 3;
    int r = lp / 14, c = lp - r * 14;
    int gy = y0 - 3 + r, gx = x0 - 3 + c;
    uint4v val = {0u, 0u, 0u, 0u};
    if ((unsigned)gy < 56u && (unsigned)gx < 56u)
      val = *(const uint4v*)(qimg + (size_t)(gy * 56 + gx) * 64 + slot * 16);
    *(uint4v*)&patchB[lp * 64 + ((slot ^ ((lp >> 1) & 3)) << 4)] = val;
  }
  __syncthreads();

  int lane = tid & 63, wid = tid >> 6;
  int Mtile = wid & 1, Ntile = wid >> 1;
  int n = lane & 31, hi = lane >> 5;
  int py = Ntile * 4 + (n >> 3), px = n & 7;
  int lpb = py * 14 + px;
  f32x16 acc0, acc1;
#pragma unroll
  for (int i = 0; i < 16; i++) { acc0[i] = 0.f; acc1[i] = 0.f; }

  const u8* Aw = wTs8 + Mtile * 2048 + lane * 32;
#pragma unroll
  for (int tap = 0; tap < KWIN; tap++) {
    int lp_ = lpb + LPOF(tap);
    const int4x* ap = (const int4x*)(Aw + tap * 4096);
    int4x alo = ap[0], ahi = ap[1];
    int sw = (lp_ >> 1) & 3;
    int4x blo = *(const int4x*)&patchB[lp_ * 64 + (((2 * hi) ^ sw) << 4)];
    int4x bhi = *(const int4x*)&patchB[lp_ * 64 + (((2 * hi + 1) ^ sw) << 4)];
    int8x a = __builtin_shufflevector(alo, ahi, 0, 1, 2, 3, 4, 5, 6, 7);
    int8x b = __builtin_shufflevector(blo, bhi, 0, 1, 2, 3, 4, 5, 6, 7);
    if (tap & 1)
      acc1 = __builtin_amdgcn_mfma_scale_f32_32x32x64_f8f6f4(
          a, b, acc1, 0, 0, 0, 127, 0, 127);
    else
      acc0 = __builtin_amdgcn_mfma_scale_f32_32x32x64_f8f6f4(
          a, b, acc0, 0, 0, 0, 127, 0, 127);
  }

  // ---- fused tail ----
  __syncthreads();
  float* smx = (float*)shraw;            // 49 x 65 x 4 = 12740 B
  u16* vp = shraw + 6376;                // [196 pix][VPS] bf16 (15680 B)
  int head = img % NHEADS;
#pragma unroll
  for (int r = 0; r < 16; r++) {
    int ko = Mtile * 32 + (r & 3) + 8 * (r >> 2) + 4 * hi;
    if (ko < KWIN)
      smx[ko * SMS + Ntile * 32 + n] =
          acc0[r] + acc1[r] + dm_b[ko] + rel_bias[ko * NHEADS + head];
  }
  const u16* vbase = vT + (size_t)img * PIX * 32;
  for (int idx = tid; idx < 784; idx += 256) {
    int g = idx & 3, lp = idx >> 2;
    int r = lp / 14, c = lp - r * 14;
    int gy = y0 - 3 + r, gx = x0 - 3 + c;
    uint4v val = {0u, 0u, 0u, 0u};
    if ((unsigned)gy < 56u && (unsigned)gx < 56u)
      val = *(const uint4v*)(vbase + (size_t)(gy * 56 + gx) * 32 + g * 8);
    *(uint4v*)&vp[lp * VPS + g * 8] = val;
  }
  __syncthreads();
  {
    int pxs = tid >> 2, q4 = tid & 3;
    int k0 = q4 * 13;
    int k1 = (q4 == 3) ? KWIN : k0 + 13;
    float m = -1e30f;
    for (int k = k0; k < k1; k++) m = fmaxf(m, smx[k * SMS + pxs]);
    m = fmaxf(m, __shfl_xor(m, 1, 64));
    m = fmaxf(m, __shfl_xor(m, 2, 64));
    float ssum = 0.f;
    for (int k = k0; k < k1; k++) {
      float e = __expf(smx[k * SMS + pxs] - m);
      smx[k * SMS + pxs] = e;
      ssum += e;
    }
    ssum += __shfl_xor(ssum, 1, 64);
    ssum += __shfl_xor(ssum, 2, 64);
    float inv = 1.f / ssum;
    for (int k = k0; k < k1; k++) smx[k * SMS + pxs] *= inv;
  }
  __syncthreads();
  int pxl = tid & 63, co = tid >> 6;
  int pyy = pxl >> 3, pxx = pxl & 7;
  float o8[8] = {0.f, 0.f, 0.f, 0.f, 0.f, 0.f, 0.f, 0.f};
#pragma unroll
  for (int kh = 0; kh < 7; kh++) {
#pragma unroll
    for (int kw = 0; kw < 7; kw++) {
      float p = smx[(kh * 7 + kw) * SMS + pxl];
      bf16x8 v = *(const bf16x8*)&vp[((pyy + kh) * 14 + pxx + kw) * VPS + co * 8];
#pragma unroll
      for (int j = 0; j < 8; j++) o8[j] += p * (float)v[j];
    }
  }
  int gp = (y0 + pyy) * 56 + x0 + pxx;
  int b = img / NHEADS;
  __hip_bfloat16 ob[8];
#pragma unroll
  for (int j = 0; j < 8; j++) ob[j] = __float2bfloat16(o8[j]);
  *(uint4v*)(attnoT + ((size_t)b * PIX + gp) * CDIM + head * 32 + co * 8) = *(uint4v*)ob;
}

// ---------------- launch ----------------------------------------------------
extern "C" void kernel_launch(void* const* d_in, const int* in_sizes, int n_in,
                              void* d_out, int out_size, void* d_ws, size_t ws_size,
                              hipStream_t stream) {
  const float* x        = (const float*)d_in[0];
  const float* bn_gamma = (const float*)d_in[1];
  const float* bn_beta  = (const float*)d_in[2];
  const float* qkv_w    = (const float*)d_in[3];
  const float* qkv_b    = (const float*)d_in[4];
  const float* dm_w     = (const float*)d_in[5];
  const float* dm_b     = (const float*)d_in[6];
  const float* rel_bias = (const float*)d_in[7];
  const float* proj_w   = (const float*)d_in[8];
  const float* proj_b   = (const float*)d_in[9];
  const float* c1_w     = (const float*)d_in[10];
  const float* c1_b     = (const float*)d_in[11];
  const float* c2_w     = (const float*)d_in[12];
  const float* c2_b     = (const float*)d_in[13];
  float* out = (float*)d_out;
  float* ws  = (float*)d_ws;

  float* stats    = ws;                          // 384 f
  float* b_eff    = stats + 384;                 // 576 f
  u8*    pk_qkv8  = (u8*)(b_eff + 576);          // 110592 B
  u8*    pk_proj8 = pk_qkv8 + 110592;            // 36864 B
  u8*    pk_c18   = pk_proj8 + 36864;            // 147456 B
  u8*    pk_c28   = pk_c18 + 147456;             // 147456 B
  u8*    wTs8     = pk_c28 + 147456;             // 200704 B
  u16*   spare    = (u16*)(wTs8 + 200704);       // 4816896 u16 (hT alias)
  u8*    qk8      = (u8*)(spare + 4816896);      // 4816896 B fp8
  u16*   vT       = (u16*)(qk8 + 4816896);       // 2408448 u16
  u16*   attnoT   = vT + 2408448;                // 2408448 u16
  float* x1       = (float*)(attnoT + 2408448);  // 2408448 f
  u16*   x1T      = (u16*)(x1 + 2408448);        // 2408448 u16
  u16*   hT       = spare;                       // alias over dead spare+qk8+vT

  bn_stats_k<<<CDIM, 256, 0, stream>>>(x, stats);
  prep3_k<<<825, 256, 0, stream>>>(dm_w, wTs8, proj_w, pk_proj8, c1_w, pk_c18,
                                   c2_w, pk_c28);
  fold_pack_k<<<576, 192, 0, stream>>>(qkv_w, qkv_b, bn_gamma, bn_beta, stats,
                                       pk_qkv8, b_eff);

  mgemm_k<MG_QKV><<<dim3(49, 9), 256, 0, stream>>>(
      nullptr, pk_qkv8, b_eff, nullptr, nullptr, vT, qk8, x, 192);
  attn_fused_k<<<NIMG * 49, 256, 0, stream>>>(qk8, wTs8, vT, dm_b, rel_bias, attnoT);
  mgemm_k<MG_PROJ><<<dim3(49, 3), 256, 0, stream>>>(
      attnoT, pk_proj8, proj_b, x1, x1T, nullptr, nullptr, x, 192);
  mgemm_k<MG_GELU><<<dim3(49, 12), 256, 0, stream>>>(
      x1T, pk_c18, c1_b, nullptr, hT, nullptr, nullptr, nullptr, 192);
  mgemm_k<MG_C2><<<dim3(49, 3), 256, 0, stream>>>(
      hT, pk_c28, c2_b, out, nullptr, nullptr, nullptr, x1, 768);
}

// Round 16
// 135.348 us; speedup vs baseline: 1.4170x; 1.4170x over previous
//
#include <hip/hip_runtime.h>
#include <hip/hip_bf16.h>
#include <math.h>

#define CDIM 192
#define NHEADS 6
#define WIN 7
#define KWIN 49
#define BATCH 4
#define PIX 3136      // 56*56
#define NPIX 12544    // BATCH*PIX
#define NIMG 24       // BATCH*NHEADS
#define EPSV 1e-5f

typedef __bf16 bf16x8 __attribute__((ext_vector_type(8)));
typedef float f32x16 __attribute__((ext_vector_type(16)));
typedef unsigned int uint4v __attribute__((ext_vector_type(4)));
typedef unsigned int uint2v __attribute__((ext_vector_type(2)));
typedef int int4x __attribute__((ext_vector_type(4)));
typedef int int8x __attribute__((ext_vector_type(8)));
typedef unsigned short u16;
typedef unsigned char u8;

__device__ inline u8 f32_to_fp8(float v) {
  return (u8)(__builtin_amdgcn_cvt_pk_fp8_f32(v, 0.f, 0, false) & 0xFF);
}

// 8 bf16 (as uint4v) -> 8 fp8 bytes (uint2v)
__device__ inline uint2v bf8_to_fp8x8(uint4v v) {
  const u16* h = (const u16*)&v;
  float f[8];
#pragma unroll
  for (int e = 0; e < 8; e++) {
    unsigned u = ((unsigned)h[e]) << 16;
    f[e] = __builtin_bit_cast(float, u);
  }
  int lo = __builtin_amdgcn_cvt_pk_fp8_f32(f[0], f[1], 0, false);
  lo = __builtin_amdgcn_cvt_pk_fp8_f32(f[2], f[3], lo, true);
  int hi = __builtin_amdgcn_cvt_pk_fp8_f32(f[4], f[5], 0, false);
  hi = __builtin_amdgcn_cvt_pk_fp8_f32(f[6], f[7], hi, true);
  uint2v r = {(unsigned)lo, (unsigned)hi};
  return r;
}

// ---------------- BN stats ---------------------------------------------------
__global__ __launch_bounds__(256) void bn_stats_k(const float* __restrict__ x,
                                                  float* __restrict__ stats) {
  int c = blockIdx.x;
  float s = 0.f, q = 0.f;
  for (int n = threadIdx.x; n < BATCH * PIX; n += 256) {
    int b = n / PIX, p = n - b * PIX;
    float v = x[((size_t)b * CDIM + c) * PIX + p];
    s += v; q += v * v;
  }
  __shared__ float rs[256], rq[256];
  rs[threadIdx.x] = s; rq[threadIdx.x] = q;
  __syncthreads();
  for (int st = 128; st > 0; st >>= 1) {
    if (threadIdx.x < st) { rs[threadIdx.x] += rs[threadIdx.x + st]; rq[threadIdx.x] += rq[threadIdx.x + st]; }
    __syncthreads();
  }
  if (threadIdx.x == 0) {
    float mean = rs[0] / (float)(BATCH * PIX);
    float var = rq[0] / (float)(BATCH * PIX) - mean * mean;
    stats[c] = mean;
    stats[CDIM + c] = rsqrtf(var + EPSV);
  }
}

// ------- fold BN + q-scale into qkv weights, writing PACKED frags directly --
__global__ __launch_bounds__(192) void fold_pack_k(
    const float* __restrict__ qkv_w, const float* __restrict__ qkv_b,
    const float* __restrict__ gamma, const float* __restrict__ beta,
    const float* __restrict__ stats, u16* __restrict__ pk_qkv,
    float* __restrict__ b_eff) {
  int o = blockIdx.x, c = threadIdx.x;
  float alpha = gamma[c] * stats[CDIM + c];
  float shift = beta[c] - stats[c] * alpha;
  float w = qkv_w[o * CDIM + c];
  float scale = (o < CDIM) ? 0.17677669529663687f : 1.f;
  int t8 = ((((o >> 5) * 12 + (c >> 4)) * 64 + (((c >> 3) & 1) * 32 + (o & 31))) << 3) + (c & 7);
  ((__hip_bfloat16*)pk_qkv)[t8] = __float2bfloat16(w * alpha * scale);
  __shared__ float r[CDIM];
  r[c] = w * shift;
  __syncthreads();
  if (c == 0) {
    float s = 0.f;
    for (int i = 0; i < CDIM; i++) s += r[i];
    b_eff[o] = (qkv_b[o] + s) * scale;
  }
}

// ---------------- generic pack helper: W[Cout][Cin] -> frag-major -----------
__device__ inline void pack_one(const float* __restrict__ W, u16* __restrict__ out,
                                int Cin, int t) {
  int lane = t & 63, rest = t >> 6;
  int nK = Cin >> 4;
  int kk = rest % nK, mtg = rest / nK;
  int o = mtg * 32 + (lane & 31), c = kk * 16 + (lane >> 5) * 8;
  const float* src = W + (size_t)o * Cin + c;
  __hip_bfloat16 tmp[8];
#pragma unroll
  for (int e = 0; e < 8; e++) tmp[e] = __float2bfloat16(src[e]);
  *(uint4v*)(out + (size_t)t * 8) = *(uint4v*)tmp;
}

// --- merged prep: dm_w K=64-frag FP8 pack + proj/c1/c2 packs ----------------
__global__ __launch_bounds__(256) void prep3_k(
    const float* __restrict__ dm_w, u8* __restrict__ wTs8,
    const float* __restrict__ proj_w, u16* __restrict__ pk_proj,
    const float* __restrict__ c1_w, u16* __restrict__ pk_c1,
    const float* __restrict__ c2_w, u16* __restrict__ pk_c2) {
  int bid = blockIdx.x, tid = threadIdx.x;
  if (bid < 784) {
    int idx = bid * 256 + tid;          // < 200704
    int e = idx & 31;
    int tmp = idx >> 5;
    int lane = tmp & 63; tmp >>= 6;
    int Mt = tmp & 1;
    int tap = tmp >> 1;                 // 0..48
    int ko = Mt * 32 + (lane & 31);
    int ci = (lane >> 5) * 32 + e;
    float v = (ko < KWIN) ? dm_w[(size_t)ko * 3136 + ci * 49 + tap] : 0.f;
    wTs8[idx] = f32_to_fp8(v);
  } else if (bid < 802) {
    int t = (bid - 784) * 256 + tid;
    if (t < 4608) pack_one(proj_w, pk_proj, 192, t);
  } else if (bid < 874) {
    int t = (bid - 802) * 256 + tid;
    if (t < 18432) pack_one(c1_w, pk_c1, 192, t);
  } else {
    int t = (bid - 874) * 256 + tid;
    if (t < 18432) pack_one(c2_w, pk_c2, 768, t);
  }
}

// ---------------- MFMA GEMM (256px tile + A staged in LDS) ------------------
#define MG_QKV 0
#define MG_PROJ 1
#define MG_GELU 2
#define MG_C2 3
#define MGS 2056

template <int EPI>
__global__ __launch_bounds__(256, 3) void mgemm_k(
    const u16* __restrict__ Bm, const u16* __restrict__ Apk,
    const float* __restrict__ bias,
    float* __restrict__ outF, u16* __restrict__ outT, u16* __restrict__ outT2,
    u8* __restrict__ outQK8,
    const float* __restrict__ extra, int Cin) {
  __shared__ __align__(16) u16 Bs[8 * MGS];  // 32.9 KB
  __shared__ __align__(16) u16 As[4096];     // 8 KB
  int tid = threadIdx.x;
  int lane = tid & 63, wid = tid >> 6;
  int hi = lane >> 5, ln31 = lane & 31;
  int p0 = blockIdx.x * 256;
  int o0 = blockIdx.y * 64;
  int nK = Cin >> 4;
  f32x16 acc[2][2];
#pragma unroll
  for (int mt = 0; mt < 2; mt++)
#pragma unroll
    for (int nt = 0; nt < 2; nt++)
#pragma unroll
      for (int i = 0; i < 16; i++) acc[mt][nt][i] = 0.f;

  unsigned gp_s = p0 + tid;
  unsigned bb_s = gp_s / PIX, pp_s = gp_s - bb_s * PIX;

  for (int cc = 0; cc < Cin; cc += 64) {
    if (EPI == MG_QKV) {
#pragma unroll
      for (int g = 0; g < 8; g++) {
        const float* xb = extra + ((size_t)bb_s * CDIM + cc + g * 8) * PIX + pp_s;
        __hip_bfloat16 tmp[8];
#pragma unroll
        for (int e = 0; e < 8; e++) tmp[e] = __float2bfloat16(xb[(size_t)e * PIX]);
        *(uint4v*)&Bs[g * MGS + tid * 8] = *(uint4v*)tmp;
      }
    } else {
#pragma unroll
      for (int i = 0; i < 8; i++) {
        int idx = i * 256 + tid;
        int g = idx & 7, p = idx >> 3;
        uint4v v = *(const uint4v*)(Bm + (size_t)(p0 + p) * Cin + cc + g * 8);
        *(uint4v*)&Bs[g * MGS + p * 8] = v;
      }
    }
#pragma unroll
    for (int i = 0; i < 2; i++) {
      int idx = i * 256 + tid;
      int frag = idx >> 6, l64 = idx & 63;
      int mt = frag >> 2, ks = frag & 3;
      uint4v v = *(const uint4v*)(Apk +
          (size_t)(((o0 >> 5) + mt) * nK + (cc >> 4) + ks) * 512 + l64 * 8);
      *(uint4v*)&As[frag * 512 + l64 * 8] = v;
    }
    __syncthreads();
    int pA = wid * 64 + ln31;
    int pB = pA + 32;
#pragma unroll
    for (int ks = 0; ks < 4; ks++) {
      int g = ks * 2 + hi;
      bf16x8 b0 = *(const bf16x8*)&Bs[g * MGS + pA * 8];
      bf16x8 b1 = *(const bf16x8*)&Bs[g * MGS + pB * 8];
      bf16x8 a0 = *(const bf16x8*)&As[ks * 512 + lane * 8];
      bf16x8 a1 = *(const bf16x8*)&As[(4 + ks) * 512 + lane * 8];
      acc[0][0] = __builtin_amdgcn_mfma_f32_32x32x16_bf16(a0, b0, acc[0][0], 0, 0, 0);
      acc[0][1] = __builtin_amdgcn_mfma_f32_32x32x16_bf16(a0, b1, acc[0][1], 0, 0, 0);
      acc[1][0] = __builtin_amdgcn_mfma_f32_32x32x16_bf16(a1, b0, acc[1][0], 0, 0, 0);
      acc[1][1] = __builtin_amdgcn_mfma_f32_32x32x16_bf16(a1, b1, acc[1][1], 0, 0, 0);
    }
    __syncthreads();
  }

  // ---- epilogue ----
  if (EPI == MG_C2) {
#pragma unroll
    for (int mt = 0; mt < 2; mt++)
#pragma unroll
      for (int r = 0; r < 16; r++) {
        int o = o0 + mt * 32 + (r & 3) + 8 * (r >> 2) + 4 * hi;
        float bv = bias[o];
#pragma unroll
        for (int nt = 0; nt < 2; nt++) {
          unsigned gp = p0 + wid * 64 + nt * 32 + ln31;
          unsigned bb = gp / PIX, pp = gp - bb * PIX;
          size_t oi = ((size_t)bb * CDIM + o) * PIX + pp;
          outF[oi] = acc[mt][nt][r] + bv + extra[oi];
        }
      }
  } else {
#pragma unroll
    for (int mt = 0; mt < 2; mt++)
#pragma unroll
      for (int r = 0; r < 16; r++) {
        int o_loc = mt * 32 + (r & 3) + 8 * (r >> 2) + 4 * hi;
        int o = o0 + o_loc;
        float bv = bias[o];
#pragma unroll
        for (int nt = 0; nt < 2; nt++) {
          int p_loc = wid * 64 + nt * 32 + ln31;
          float val = acc[mt][nt][r] + bv;
          if (EPI == MG_PROJ) {
            unsigned gp = p0 + p_loc;
            unsigned bb = gp / PIX, pp = gp - bb * PIX;
            size_t oi = ((size_t)bb * CDIM + o) * PIX + pp;
            val += extra[oi];
            outF[oi] = val;
          }
          if (EPI == MG_GELU)
            val = 0.5f * val * (1.f + erff(val * 0.70710678118654752f));
          *(__hip_bfloat16*)&Bs[p_loc * 64 + (((o_loc >> 3) ^ (p_loc & 7)) << 3) + (o_loc & 7)] =
              __float2bfloat16(val);
        }
      }
    __syncthreads();
    int prow = wid * 64 + lane;
    int psw = prow & 7;
    uint4v r8[8];
#pragma unroll
    for (int g = 0; g < 8; g++)
      r8[g] = *(const uint4v*)&Bs[prow * 64 + ((g ^ psw) << 3)];
    unsigned gp = p0 + prow;
    if (EPI == MG_QKV) {
      unsigned bb = gp / PIX, pp = gp - bb * PIX;
      int s = o0 / 192;               // 0=q, 1=k, 2=v
      int rr = o0 - s * 192;
      int h0 = rr >> 5;
      if (s < 2) {
        uint2v c0 = bf8_to_fp8x8(r8[0]), c1 = bf8_to_fp8x8(r8[1]);
        uint2v c2 = bf8_to_fp8x8(r8[2]), c3 = bf8_to_fp8x8(r8[3]);
        uint2v c4 = bf8_to_fp8x8(r8[4]), c5 = bf8_to_fp8x8(r8[5]);
        uint2v c6 = bf8_to_fp8x8(r8[6]), c7 = bf8_to_fp8x8(r8[7]);
        uint4v w0 = {c0[0], c0[1], c1[0], c1[1]};
        uint4v w1 = {c2[0], c2[1], c3[0], c3[1]};
        uint4v w2 = {c4[0], c4[1], c5[0], c5[1]};
        uint4v w3 = {c6[0], c6[1], c7[0], c7[1]};
        u8* d0 = outQK8 + ((size_t)(bb * NHEADS + h0) * PIX + pp) * 64 + s * 32;
        u8* d1 = outQK8 + ((size_t)(bb * NHEADS + h0 + 1) * PIX + pp) * 64 + s * 32;
        *(uint4v*)(d0) = w0; *(uint4v*)(d0 + 16) = w1;
        *(uint4v*)(d1) = w2; *(uint4v*)(d1 + 16) = w3;
      } else {                        // v -> vT[img][pix][32] bf16
        u16* d0 = outT2 + ((size_t)(bb * NHEADS + h0) * PIX + pp) * 32;
        u16* d1 = outT2 + ((size_t)(bb * NHEADS + h0 + 1) * PIX + pp) * 32;
        *(uint4v*)(d0) = r8[0]; *(uint4v*)(d0 + 8) = r8[1];
        *(uint4v*)(d0 + 16) = r8[2]; *(uint4v*)(d0 + 24) = r8[3];
        *(uint4v*)(d1) = r8[4]; *(uint4v*)(d1 + 8) = r8[5];
        *(uint4v*)(d1 + 16) = r8[6]; *(uint4v*)(d1 + 24) = r8[7];
      }
    } else if (EPI == MG_PROJ) {
      u16* d = outT + (size_t)gp * CDIM + o0;
#pragma unroll
      for (int g = 0; g < 8; g++) *(uint4v*)(d + g * 8) = r8[g];
    } else {  // GELU -> hT [gp][768]
      u16* d = outT + (size_t)gp * 768 + o0;
#pragma unroll
      for (int g = 0; g < 8; g++) *(uint4v*)(d + g * 8) = r8[g];
    }
  }
}

// ------ 7x7 attn conv (MX-scaled fp8 K=64 MFMA) + fused softmax/PV ----------
#define VPS 40
#define SMS 65
#define DIV7(t) (((t) * 9363) >> 16)
#define LPOF(t) ((t) + 7 * DIV7(t))

__global__ __launch_bounds__(256, 4) void attn_fused_k(
    const u8* __restrict__ qk8, const u8* __restrict__ wTs8,
    const u16* __restrict__ vT,
    const float* __restrict__ dm_b, const float* __restrict__ rel_bias,
    u16* __restrict__ attnoT) {
  __shared__ __align__(16) u16 shraw[14216];   // 28432 B
  u8* patchB = (u8*)shraw;                     // phase1: 196 x 64B = 12.5 KB
  int img = blockIdx.x / 49;
  int tile = blockIdx.x % 49;
  int y0 = (tile / 7) * 8, x0 = (tile % 7) * 8;
  int tid = threadIdx.x;
  const u8* qimg = qk8 + (size_t)img * PIX * 64;
  for (int idx = tid; idx < 784; idx += 256) {
    int lp = idx >> 2, slot = idx & 3;
    int r = lp / 14, c = lp - r * 14;
    int gy = y0 - 3 + r, gx = x0 - 3 + c;
    uint4v val = {0u, 0u, 0u, 0u};
    if ((unsigned)gy < 56u && (unsigned)gx < 56u)
      val = *(const uint4v*)(qimg + (size_t)(gy * 56 + gx) * 64 + slot * 16);
    *(uint4v*)&patchB[lp * 64 + ((slot ^ ((lp >> 1) & 3)) << 4)] = val;
  }
  __syncthreads();

  int lane = tid & 63, wid = tid >> 6;
  int Mtile = wid & 1, Ntile = wid >> 1;
  int n = lane & 31, hi = lane >> 5;
  int py = Ntile * 4 + (n >> 3), px = n & 7;
  int lpb = py * 14 + px;
  f32x16 acc0, acc1;
#pragma unroll
  for (int i = 0; i < 16; i++) { acc0[i] = 0.f; acc1[i] = 0.f; }

  const u8* Aw = wTs8 + Mtile * 2048 + lane * 32;
#pragma unroll
  for (int tap = 0; tap < KWIN; tap++) {
    int lp_ = lpb + LPOF(tap);
    const int4x* ap = (const int4x*)(Aw + tap * 4096);
    int4x alo = ap[0], ahi = ap[1];
    int sw = (lp_ >> 1) & 3;
    int4x blo = *(const int4x*)&patchB[lp_ * 64 + (((2 * hi) ^ sw) << 4)];
    int4x bhi = *(const int4x*)&patchB[lp_ * 64 + (((2 * hi + 1) ^ sw) << 4)];
    int8x a = __builtin_shufflevector(alo, ahi, 0, 1, 2, 3, 4, 5, 6, 7);
    int8x b = __builtin_shufflevector(blo, bhi, 0, 1, 2, 3, 4, 5, 6, 7);
    if (tap & 1)
      acc1 = __builtin_amdgcn_mfma_scale_f32_32x32x64_f8f6f4(
          a, b, acc1, 0, 0, 0, 127, 0, 127);
    else
      acc0 = __builtin_amdgcn_mfma_scale_f32_32x32x64_f8f6f4(
          a, b, acc0, 0, 0, 0, 127, 0, 127);
  }

  // ---- fused tail: logits -> smx[49][SMS], v-patch -> vp, softmax, PV ------
  __syncthreads();
  float* smx = (float*)shraw;            // 49 x 65 x 4 = 12740 B
  u16* vp = shraw + 6376;                // [196 pix][VPS] bf16 (15680 B)
  int head = img % NHEADS;
#pragma unroll
  for (int r = 0; r < 16; r++) {
    int ko = Mtile * 32 + (r & 3) + 8 * (r >> 2) + 4 * hi;
    if (ko < KWIN)
      smx[ko * SMS + Ntile * 32 + n] =
          acc0[r] + acc1[r] + dm_b[ko] + rel_bias[ko * NHEADS + head];
  }
  const u16* vbase = vT + (size_t)img * PIX * 32;
  for (int idx = tid; idx < 784; idx += 256) {
    int g = idx & 3, lp = idx >> 2;
    int r = lp / 14, c = lp - r * 14;
    int gy = y0 - 3 + r, gx = x0 - 3 + c;
    uint4v val = {0u, 0u, 0u, 0u};
    if ((unsigned)gy < 56u && (unsigned)gx < 56u)
      val = *(const uint4v*)(vbase + (size_t)(gy * 56 + gx) * 32 + g * 8);
    *(uint4v*)&vp[lp * VPS + g * 8] = val;
  }
  __syncthreads();
  {
    int pxs = tid >> 2, q4 = tid & 3;
    int k0 = q4 * 13;
    int k1 = (q4 == 3) ? KWIN : k0 + 13;
    float m = -1e30f;
    for (int k = k0; k < k1; k++) m = fmaxf(m, smx[k * SMS + pxs]);
    m = fmaxf(m, __shfl_xor(m, 1, 64));
    m = fmaxf(m, __shfl_xor(m, 2, 64));
    float ssum = 0.f;
    for (int k = k0; k < k1; k++) {
      float e = __expf(smx[k * SMS + pxs] - m);
      smx[k * SMS + pxs] = e;
      ssum += e;
    }
    ssum += __shfl_xor(ssum, 1, 64);
    ssum += __shfl_xor(ssum, 2, 64);
    float inv = 1.f / ssum;
    for (int k = k0; k < k1; k++) smx[k * SMS + pxs] *= inv;
  }
  __syncthreads();
  int pxl = tid & 63, co = tid >> 6;
  int pyy = pxl >> 3, pxx = pxl & 7;
  float o8[8] = {0.f, 0.f, 0.f, 0.f, 0.f, 0.f, 0.f, 0.f};
#pragma unroll
  for (int kh = 0; kh < 7; kh++) {
#pragma unroll
    for (int kw = 0; kw < 7; kw++) {
      float p = smx[(kh * 7 + kw) * SMS + pxl];
      bf16x8 v = *(const bf16x8*)&vp[((pyy + kh) * 14 + pxx + kw) * VPS + co * 8];
#pragma unroll
      for (int j = 0; j < 8; j++) o8[j] += p * (float)v[j];
    }
  }
  int gp = (y0 + pyy) * 56 + x0 + pxx;
  int b = img / NHEADS;
  __hip_bfloat16 ob[8];
#pragma unroll
  for (int j = 0; j < 8; j++) ob[j] = __float2bfloat16(o8[j]);
  *(uint4v*)(attnoT + ((size_t)b * PIX + gp) * CDIM + head * 32 + co * 8) = *(uint4v*)ob;
}

// ---------------- launch ----------------------------------------------------
extern "C" void kernel_launch(void* const* d_in, const int* in_sizes, int n_in,
                              void* d_out, int out_size, void* d_ws, size_t ws_size,
                              hipStream_t stream) {
  const float* x        = (const float*)d_in[0];
  const float* bn_gamma = (const float*)d_in[1];
  const float* bn_beta  = (const float*)d_in[2];
  const float* qkv_w    = (const float*)d_in[3];
  const float* qkv_b    = (const float*)d_in[4];
  const float* dm_w     = (const float*)d_in[5];
  const float* dm_b     = (const float*)d_in[6];
  const float* rel_bias = (const float*)d_in[7];
  const float* proj_w   = (const float*)d_in[8];
  const float* proj_b   = (const float*)d_in[9];
  const float* c1_w     = (const float*)d_in[10];
  const float* c1_b     = (const float*)d_in[11];
  const float* c2_w     = (const float*)d_in[12];
  const float* c2_b     = (const float*)d_in[13];
  float* out = (float*)d_out;
  float* ws  = (float*)d_ws;

  float* stats   = ws;                          // 384 f
  float* b_eff   = stats + 384;                 // 576 f
  u16*   pk_qkv  = (u16*)(b_eff + 576);         // 110592 u16
  u16*   pk_proj = pk_qkv + 110592;             // 36864
  u16*   pk_c1   = pk_proj + 36864;             // 147456
  u16*   pk_c2   = pk_c1 + 147456;              // 147456
  u8*    wTs8    = (u8*)(pk_c2 + 147456);       // 200704 B (fp8 K=64 frags)
  u16*   spare   = (u16*)(wTs8 + 200704);       // 4816896 u16 (hT alias head)
  u8*    qk8     = (u8*)(spare + 4816896);      // 4816896 B fp8
  u16*   vT      = (u16*)(qk8 + 4816896);       // 2408448 u16
  u16*   attnoT  = vT + 2408448;                // 2408448 u16
  float* x1      = (float*)(attnoT + 2408448);  // 2408448 f
  u16*   x1T     = (u16*)(x1 + 2408448);        // 2408448 u16
  u16*   hT      = spare;  // 9633792 u16 over dead spare+qk8+vT

  bn_stats_k<<<CDIM, 256, 0, stream>>>(x, stats);
  prep3_k<<<946, 256, 0, stream>>>(dm_w, wTs8, proj_w, pk_proj, c1_w, pk_c1,
                                   c2_w, pk_c2);
  fold_pack_k<<<576, 192, 0, stream>>>(qkv_w, qkv_b, bn_gamma, bn_beta, stats,
                                       pk_qkv, b_eff);

  mgemm_k<MG_QKV><<<dim3(49, 9), 256, 0, stream>>>(
      nullptr, pk_qkv, b_eff, nullptr, nullptr, vT, qk8, x, 192);
  attn_fused_k<<<NIMG * 49, 256, 0, stream>>>(qk8, wTs8, vT, dm_b, rel_bias, attnoT);
  mgemm_k<MG_PROJ><<<dim3(49, 3), 256, 0, stream>>>(
      attnoT, pk_proj, proj_b, x1, x1T, nullptr, nullptr, x, 192);
  mgemm_k<MG_GELU><<<dim3(49, 12), 256, 0, stream>>>(
      x1T, pk_c1, c1_b, nullptr, hT, nullptr, nullptr, nullptr, 192);
  mgemm_k<MG_C2><<<dim3(49, 3), 256, 0, stream>>>(
      hT, pk_c2, c2_b, out, nullptr, nullptr, nullptr, x1, 768);
}

// Round 17
// 120.914 us; speedup vs baseline: 1.5862x; 1.1194x over previous
//
#include <hip/hip_runtime.h>
#include <hip/hip_bf16.h>
#include <math.h>

#define CDIM 192
#define NHEADS 6
#define WIN 7
#define KWIN 49
#define BATCH 4
#define PIX 3136      // 56*56
#define NPIX 12544    // BATCH*PIX
#define NIMG 24       // BATCH*NHEADS
#define EPSV 1e-5f

typedef __bf16 bf16x8 __attribute__((ext_vector_type(8)));
typedef float f32x16 __attribute__((ext_vector_type(16)));
typedef unsigned int uint4v __attribute__((ext_vector_type(4)));
typedef unsigned int uint2v __attribute__((ext_vector_type(2)));
typedef int int4x __attribute__((ext_vector_type(4)));
typedef int int8x __attribute__((ext_vector_type(8)));
typedef unsigned short u16;
typedef unsigned char u8;

__device__ inline u8 f32_to_fp8(float v) {
  return (u8)(__builtin_amdgcn_cvt_pk_fp8_f32(v, 0.f, 0, false) & 0xFF);
}

// 8 bf16 (as uint4v) -> 8 fp8 bytes (uint2v)
__device__ inline uint2v bf8_to_fp8x8(uint4v v) {
  const u16* h = (const u16*)&v;
  float f[8];
#pragma unroll
  for (int e = 0; e < 8; e++) {
    unsigned u = ((unsigned)h[e]) << 16;
    f[e] = __builtin_bit_cast(float, u);
  }
  int lo = __builtin_amdgcn_cvt_pk_fp8_f32(f[0], f[1], 0, false);
  lo = __builtin_amdgcn_cvt_pk_fp8_f32(f[2], f[3], lo, true);
  int hi = __builtin_amdgcn_cvt_pk_fp8_f32(f[4], f[5], 0, false);
  hi = __builtin_amdgcn_cvt_pk_fp8_f32(f[6], f[7], hi, true);
  uint2v r = {(unsigned)lo, (unsigned)hi};
  return r;
}

// ---------------- BN stats ---------------------------------------------------
__global__ __launch_bounds__(256) void bn_stats_k(const float* __restrict__ x,
                                                  float* __restrict__ stats) {
  int c = blockIdx.x;
  float s = 0.f, q = 0.f;
  for (int n = threadIdx.x; n < BATCH * PIX; n += 256) {
    int b = n / PIX, p = n - b * PIX;
    float v = x[((size_t)b * CDIM + c) * PIX + p];
    s += v; q += v * v;
  }
  __shared__ float rs[256], rq[256];
  rs[threadIdx.x] = s; rq[threadIdx.x] = q;
  __syncthreads();
  for (int st = 128; st > 0; st >>= 1) {
    if (threadIdx.x < st) { rs[threadIdx.x] += rs[threadIdx.x + st]; rq[threadIdx.x] += rq[threadIdx.x + st]; }
    __syncthreads();
  }
  if (threadIdx.x == 0) {
    float mean = rs[0] / (float)(BATCH * PIX);
    float var = rq[0] / (float)(BATCH * PIX) - mean * mean;
    stats[c] = mean;
    stats[CDIM + c] = rsqrtf(var + EPSV);
  }
}

// ------- fold BN + q-scale into qkv weights, writing PACKED frags directly --
__global__ __launch_bounds__(192) void fold_pack_k(
    const float* __restrict__ qkv_w, const float* __restrict__ qkv_b,
    const float* __restrict__ gamma, const float* __restrict__ beta,
    const float* __restrict__ stats, u16* __restrict__ pk_qkv,
    float* __restrict__ b_eff) {
  int o = blockIdx.x, c = threadIdx.x;
  float alpha = gamma[c] * stats[CDIM + c];
  float shift = beta[c] - stats[c] * alpha;
  float w = qkv_w[o * CDIM + c];
  float scale = (o < CDIM) ? 0.17677669529663687f : 1.f;
  int t8 = ((((o >> 5) * 12 + (c >> 4)) * 64 + (((c >> 3) & 1) * 32 + (o & 31))) << 3) + (c & 7);
  ((__hip_bfloat16*)pk_qkv)[t8] = __float2bfloat16(w * alpha * scale);
  __shared__ float r[CDIM];
  r[c] = w * shift;
  __syncthreads();
  if (c == 0) {
    float s = 0.f;
    for (int i = 0; i < CDIM; i++) s += r[i];
    b_eff[o] = (qkv_b[o] + s) * scale;
  }
}

// ---------------- generic pack helper: W[Cout][Cin] -> frag-major -----------
__device__ inline void pack_one(const float* __restrict__ W, u16* __restrict__ out,
                                int Cin, int t) {
  int lane = t & 63, rest = t >> 6;
  int nK = Cin >> 4;
  int kk = rest % nK, mtg = rest / nK;
  int o = mtg * 32 + (lane & 31), c = kk * 16 + (lane >> 5) * 8;
  const float* src = W + (size_t)o * Cin + c;
  __hip_bfloat16 tmp[8];
#pragma unroll
  for (int e = 0; e < 8; e++) tmp[e] = __float2bfloat16(src[e]);
  *(uint4v*)(out + (size_t)t * 8) = *(uint4v*)tmp;
}

// --- merged prep: dm_w K=64-frag FP8 pack + proj/c1/c2 packs ----------------
__global__ __launch_bounds__(256) void prep3_k(
    const float* __restrict__ dm_w, u8* __restrict__ wTs8,
    const float* __restrict__ proj_w, u16* __restrict__ pk_proj,
    const float* __restrict__ c1_w, u16* __restrict__ pk_c1,
    const float* __restrict__ c2_w, u16* __restrict__ pk_c2) {
  int bid = blockIdx.x, tid = threadIdx.x;
  if (bid < 784) {
    int idx = bid * 256 + tid;          // < 200704
    int e = idx & 31;
    int tmp = idx >> 5;
    int lane = tmp & 63; tmp >>= 6;
    int Mt = tmp & 1;
    int tap = tmp >> 1;                 // 0..48
    int ko = Mt * 32 + (lane & 31);
    int ci = (lane >> 5) * 32 + e;
    float v = (ko < KWIN) ? dm_w[(size_t)ko * 3136 + ci * 49 + tap] : 0.f;
    wTs8[idx] = f32_to_fp8(v);
  } else if (bid < 802) {
    int t = (bid - 784) * 256 + tid;
    if (t < 4608) pack_one(proj_w, pk_proj, 192, t);
  } else if (bid < 874) {
    int t = (bid - 802) * 256 + tid;
    if (t < 18432) pack_one(c1_w, pk_c1, 192, t);
  } else {
    int t = (bid - 874) * 256 + tid;
    if (t < 18432) pack_one(c2_w, pk_c2, 768, t);
  }
}

// ------- MFMA GEMM: 128px x 64o tile, double-buffered async staging ---------
// Per chunk: issue next chunk's global loads -> 8 MFMAs on current LDS buf ->
// ds_write next buf -> ONE barrier. Wave owns 32px x 64o (acc[2] = Mt).
#define MG_QKV 0
#define MG_PROJ 1
#define MG_GELU 2
#define MG_C2 3
#define MG2S 1032   // B plane stride u16 (128*8 + 8 pad)

template <int EPI>
__global__ __launch_bounds__(256, 3) void mgemm_k(
    const u16* __restrict__ Bm, const u16* __restrict__ Apk,
    const float* __restrict__ bias,
    float* __restrict__ outF, u16* __restrict__ outT, u16* __restrict__ outT2,
    u8* __restrict__ outQK8,
    const float* __restrict__ extra, int Cin) {
  __shared__ __align__(16) u16 Bs[2][8 * MG2S];  // 2 x 16.5 KB
  __shared__ __align__(16) u16 As[2][4096];      // 2 x 8 KB
  int tid = threadIdx.x;
  int lane = tid & 63, wid = tid >> 6;
  int hi = lane >> 5, ln31 = lane & 31;
  int p0 = blockIdx.x * 128;
  int o0 = blockIdx.y * 64;
  int nK = Cin >> 4;
  int nKC = Cin >> 6;
  f32x16 acc[2];
#pragma unroll
  for (int mt = 0; mt < 2; mt++)
#pragma unroll
    for (int i = 0; i < 16; i++) acc[mt][i] = 0.f;

  uint4v bReg[4], aReg[2];

  auto loadC = [&](int kc) {
    int cc = kc * 64;
    if (EPI == MG_QKV) {
      int px = tid & 127, gh = tid >> 7;
      unsigned gp = p0 + px;
      unsigned bb = gp / PIX, pp = gp - bb * PIX;
#pragma unroll
      for (int j = 0; j < 4; j++) {
        int g = gh * 4 + j;
        const float* xb = extra + ((size_t)bb * CDIM + cc + g * 8) * PIX + pp;
        __hip_bfloat16 t8[8];
#pragma unroll
        for (int e = 0; e < 8; e++) t8[e] = __float2bfloat16(xb[(size_t)e * PIX]);
        bReg[j] = *(uint4v*)t8;
      }
    } else {
#pragma unroll
      for (int i = 0; i < 4; i++) {
        int idx = i * 256 + tid;
        int px = idx >> 3, g = idx & 7;
        bReg[i] = *(const uint4v*)(Bm + (size_t)(p0 + px) * Cin + cc + g * 8);
      }
    }
#pragma unroll
    for (int i = 0; i < 2; i++) {
      int idx = i * 256 + tid;
      int frag = idx >> 6, l64 = idx & 63;
      int mt = frag >> 2, ks = frag & 3;
      aReg[i] = *(const uint4v*)(Apk +
          (size_t)(((o0 >> 5) + mt) * nK + kc * 4 + ks) * 512 + l64 * 8);
    }
  };
  auto storeC = [&](int buf) {
    if (EPI == MG_QKV) {
      int px = tid & 127, gh = tid >> 7;
#pragma unroll
      for (int j = 0; j < 4; j++)
        *(uint4v*)&Bs[buf][(gh * 4 + j) * MG2S + px * 8] = bReg[j];
    } else {
#pragma unroll
      for (int i = 0; i < 4; i++) {
        int idx = i * 256 + tid;
        int px = idx >> 3, g = idx & 7;
        *(uint4v*)&Bs[buf][g * MG2S + px * 8] = bReg[i];
      }
    }
#pragma unroll
    for (int i = 0; i < 2; i++) {
      int idx = i * 256 + tid;
      int frag = idx >> 6, l64 = idx & 63;
      *(uint4v*)&As[buf][frag * 512 + l64 * 8] = aReg[i];
    }
  };

  loadC(0);
  storeC(0);
  __syncthreads();
  int pxw = wid * 32 + ln31;
  for (int kc = 0; kc < nKC; kc++) {
    int cur = kc & 1;
    bool more = (kc + 1 < nKC);
    if (more) loadC(kc + 1);            // global loads overlap MFMAs below
#pragma unroll
    for (int ks = 0; ks < 4; ks++) {
      int g = ks * 2 + hi;
      bf16x8 b  = *(const bf16x8*)&Bs[cur][g * MG2S + pxw * 8];
      bf16x8 a0 = *(const bf16x8*)&As[cur][ks * 512 + lane * 8];
      bf16x8 a1 = *(const bf16x8*)&As[cur][(4 + ks) * 512 + lane * 8];
      acc[0] = __builtin_amdgcn_mfma_f32_32x32x16_bf16(a0, b, acc[0], 0, 0, 0);
      acc[1] = __builtin_amdgcn_mfma_f32_32x32x16_bf16(a1, b, acc[1], 0, 0, 0);
    }
    if (more) storeC(cur ^ 1);          // write other buffer (no race)
    __syncthreads();
  }

  // ---- epilogue ----
  if (EPI == MG_C2) {
#pragma unroll
    for (int mt = 0; mt < 2; mt++)
#pragma unroll
      for (int r = 0; r < 16; r++) {
        int o = o0 + mt * 32 + (r & 3) + 8 * (r >> 2) + 4 * hi;
        float bv = bias[o];
        unsigned gp = p0 + pxw;
        unsigned bb = gp / PIX, pp = gp - bb * PIX;
        size_t oi = ((size_t)bb * CDIM + o) * PIX + pp;
        outF[oi] = acc[mt][r] + bv + extra[oi];
      }
  } else {
    u16* scratch = (u16*)Bs;            // 128 rows x 64 o x 2B = 16 KB
#pragma unroll
    for (int mt = 0; mt < 2; mt++)
#pragma unroll
      for (int r = 0; r < 16; r++) {
        int o_loc = mt * 32 + (r & 3) + 8 * (r >> 2) + 4 * hi;
        int o = o0 + o_loc;
        float bv = bias[o];
        int p_loc = pxw;
        float val = acc[mt][r] + bv;
        if (EPI == MG_PROJ) {
          unsigned gp = p0 + p_loc;
          unsigned bb = gp / PIX, pp = gp - bb * PIX;
          size_t oi = ((size_t)bb * CDIM + o) * PIX + pp;
          val += extra[oi];
          outF[oi] = val;
        }
        if (EPI == MG_GELU)
          val = 0.5f * val * (1.f + erff(val * 0.70710678118654752f));
        *(__hip_bfloat16*)&scratch[p_loc * 64 + (((o_loc >> 3) ^ (p_loc & 7)) << 3) + (o_loc & 7)] =
            __float2bfloat16(val);
      }
    // wave-local rows: thread tid reads row tid>>1 (written by its own wave)
    int prow = tid >> 1, half = tid & 1;
    int psw = prow & 7;
    uint4v r4[4];
#pragma unroll
    for (int j = 0; j < 4; j++)
      r4[j] = *(const uint4v*)&scratch[prow * 64 + ((((half << 2) + j) ^ psw) << 3)];
    unsigned gp = p0 + prow;
    if (EPI == MG_QKV) {
      unsigned bb = gp / PIX, pp = gp - bb * PIX;
      int s = o0 / 192;               // 0=q, 1=k, 2=v
      int h0 = ((o0 - s * 192) >> 5) + half;
      if (s < 2) {
        uint2v c0 = bf8_to_fp8x8(r4[0]), c1 = bf8_to_fp8x8(r4[1]);
        uint2v c2 = bf8_to_fp8x8(r4[2]), c3 = bf8_to_fp8x8(r4[3]);
        uint4v w0 = {c0[0], c0[1], c1[0], c1[1]};
        uint4v w1 = {c2[0], c2[1], c3[0], c3[1]};
        u8* d = outQK8 + ((size_t)(bb * NHEADS + h0) * PIX + pp) * 64 + s * 32;
        *(uint4v*)(d) = w0; *(uint4v*)(d + 16) = w1;
      } else {                        // v -> vT[img][pix][32] bf16
        u16* d = outT2 + ((size_t)(bb * NHEADS + h0) * PIX + pp) * 32;
        *(uint4v*)(d) = r4[0]; *(uint4v*)(d + 8) = r4[1];
        *(uint4v*)(d + 16) = r4[2]; *(uint4v*)(d + 24) = r4[3];
      }
    } else if (EPI == MG_PROJ) {
      u16* d = outT + (size_t)gp * CDIM + o0 + half * 32;
#pragma unroll
      for (int j = 0; j < 4; j++) *(uint4v*)(d + j * 8) = r4[j];
    } else {  // GELU -> hT [gp][768]
      u16* d = outT + (size_t)gp * 768 + o0 + half * 32;
#pragma unroll
      for (int j = 0; j < 4; j++) *(uint4v*)(d + j * 8) = r4[j];
    }
  }
}

// ------ 7x7 attn conv (MX-scaled fp8 K=64 MFMA) + fused softmax/PV ----------
#define VPS 40
#define SMS 65
#define DIV7(t) (((t) * 9363) >> 16)
#define LPOF(t) ((t) + 7 * DIV7(t))

__global__ __launch_bounds__(256, 4) void attn_fused_k(
    const u8* __restrict__ qk8, const u8* __restrict__ wTs8,
    const u16* __restrict__ vT,
    const float* __restrict__ dm_b, const float* __restrict__ rel_bias,
    u16* __restrict__ attnoT) {
  __shared__ __align__(16) u16 shraw[14216];   // 28432 B
  u8* patchB = (u8*)shraw;                     // phase1: 196 x 64B = 12.5 KB
  int img = blockIdx.x / 49;
  int tile = blockIdx.x % 49;
  int y0 = (tile / 7) * 8, x0 = (tile % 7) * 8;
  int tid = threadIdx.x;
  const u8* qimg = qk8 + (size_t)img * PIX * 64;
  for (int idx = tid; idx < 784; idx += 256) {
    int lp = idx >> 2, slot = idx & 3;
    int r = lp / 14, c = lp - r * 14;
    int gy = y0 - 3 + r, gx = x0 - 3 + c;
    uint4v val = {0u, 0u, 0u, 0u};
    if ((unsigned)gy < 56u && (unsigned)gx < 56u)
      val = *(const uint4v*)(qimg + (size_t)(gy * 56 + gx) * 64 + slot * 16);
    *(uint4v*)&patchB[lp * 64 + ((slot ^ ((lp >> 1) & 3)) << 4)] = val;
  }
  __syncthreads();

  int lane = tid & 63, wid = tid >> 6;
  int Mtile = wid & 1, Ntile = wid >> 1;
  int n = lane & 31, hi = lane >> 5;
  int py = Ntile * 4 + (n >> 3), px = n & 7;
  int lpb = py * 14 + px;
  f32x16 acc0, acc1;
#pragma unroll
  for (int i = 0; i < 16; i++) { acc0[i] = 0.f; acc1[i] = 0.f; }

  const u8* Aw = wTs8 + Mtile * 2048 + lane * 32;
#pragma unroll
  for (int tap = 0; tap < KWIN; tap++) {
    int lp_ = lpb + LPOF(tap);
    const int4x* ap = (const int4x*)(Aw + tap * 4096);
    int4x alo = ap[0], ahi = ap[1];
    int sw = (lp_ >> 1) & 3;
    int4x blo = *(const int4x*)&patchB[lp_ * 64 + (((2 * hi) ^ sw) << 4)];
    int4x bhi = *(const int4x*)&patchB[lp_ * 64 + (((2 * hi + 1) ^ sw) << 4)];
    int8x a = __builtin_shufflevector(alo, ahi, 0, 1, 2, 3, 4, 5, 6, 7);
    int8x b = __builtin_shufflevector(blo, bhi, 0, 1, 2, 3, 4, 5, 6, 7);
    if (tap & 1)
      acc1 = __builtin_amdgcn_mfma_scale_f32_32x32x64_f8f6f4(
          a, b, acc1, 0, 0, 0, 127, 0, 127);
    else
      acc0 = __builtin_amdgcn_mfma_scale_f32_32x32x64_f8f6f4(
          a, b, acc0, 0, 0, 0, 127, 0, 127);
  }

  // ---- fused tail: logits -> smx[49][SMS], v-patch -> vp, softmax, PV ------
  __syncthreads();
  float* smx = (float*)shraw;            // 49 x 65 x 4 = 12740 B
  u16* vp = shraw + 6376;                // [196 pix][VPS] bf16 (15680 B)
  int head = img % NHEADS;
#pragma unroll
  for (int r = 0; r < 16; r++) {
    int ko = Mtile * 32 + (r & 3) + 8 * (r >> 2) + 4 * hi;
    if (ko < KWIN)
      smx[ko * SMS + Ntile * 32 + n] =
          acc0[r] + acc1[r] + dm_b[ko] + rel_bias[ko * NHEADS + head];
  }
  const u16* vbase = vT + (size_t)img * PIX * 32;
  for (int idx = tid; idx < 784; idx += 256) {
    int g = idx & 3, lp = idx >> 2;
    int r = lp / 14, c = lp - r * 14;
    int gy = y0 - 3 + r, gx = x0 - 3 + c;
    uint4v val = {0u, 0u, 0u, 0u};
    if ((unsigned)gy < 56u && (unsigned)gx < 56u)
      val = *(const uint4v*)(vbase + (size_t)(gy * 56 + gx) * 32 + g * 8);
    *(uint4v*)&vp[lp * VPS + g * 8] = val;
  }
  __syncthreads();
  {
    int pxs = tid >> 2, q4 = tid & 3;
    int k0 = q4 * 13;
    int k1 = (q4 == 3) ? KWIN : k0 + 13;
    float m = -1e30f;
    for (int k = k0; k < k1; k++) m = fmaxf(m, smx[k * SMS + pxs]);
    m = fmaxf(m, __shfl_xor(m, 1, 64));
    m = fmaxf(m, __shfl_xor(m, 2, 64));
    float ssum = 0.f;
    for (int k = k0; k < k1; k++) {
      float e = __expf(smx[k * SMS + pxs] - m);
      smx[k * SMS + pxs] = e;
      ssum += e;
    }
    ssum += __shfl_xor(ssum, 1, 64);
    ssum += __shfl_xor(ssum, 2, 64);
    float inv = 1.f / ssum;
    for (int k = k0; k < k1; k++) smx[k * SMS + pxs] *= inv;
  }
  __syncthreads();
  int pxl = tid & 63, co = tid >> 6;
  int pyy = pxl >> 3, pxx = pxl & 7;
  float o8[8] = {0.f, 0.f, 0.f, 0.f, 0.f, 0.f, 0.f, 0.f};
#pragma unroll
  for (int kh = 0; kh < 7; kh++) {
#pragma unroll
    for (int kw = 0; kw < 7; kw++) {
      float p = smx[(kh * 7 + kw) * SMS + pxl];
      bf16x8 v = *(const bf16x8*)&vp[((pyy + kh) * 14 + pxx + kw) * VPS + co * 8];
#pragma unroll
      for (int j = 0; j < 8; j++) o8[j] += p * (float)v[j];
    }
  }
  int gp = (y0 + pyy) * 56 + x0 + pxx;
  int b = img / NHEADS;
  __hip_bfloat16 ob[8];
#pragma unroll
  for (int j = 0; j < 8; j++) ob[j] = __float2bfloat16(o8[j]);
  *(uint4v*)(attnoT + ((size_t)b * PIX + gp) * CDIM + head * 32 + co * 8) = *(uint4v*)ob;
}

// ---------------- launch ----------------------------------------------------
extern "C" void kernel_launch(void* const* d_in, const int* in_sizes, int n_in,
                              void* d_out, int out_size, void* d_ws, size_t ws_size,
                              hipStream_t stream) {
  const float* x        = (const float*)d_in[0];
  const float* bn_gamma = (const float*)d_in[1];
  const float* bn_beta  = (const float*)d_in[2];
  const float* qkv_w    = (const float*)d_in[3];
  const float* qkv_b    = (const float*)d_in[4];
  const float* dm_w     = (const float*)d_in[5];
  const float* dm_b     = (const float*)d_in[6];
  const float* rel_bias = (const float*)d_in[7];
  const float* proj_w   = (const float*)d_in[8];
  const float* proj_b   = (const float*)d_in[9];
  const float* c1_w     = (const float*)d_in[10];
  const float* c1_b     = (const float*)d_in[11];
  const float* c2_w     = (const float*)d_in[12];
  const float* c2_b     = (const float*)d_in[13];
  float* out = (float*)d_out;
  float* ws  = (float*)d_ws;

  float* stats   = ws;                          // 384 f
  float* b_eff   = stats + 384;                 // 576 f
  u16*   pk_qkv  = (u16*)(b_eff + 576);         // 110592 u16
  u16*   pk_proj = pk_qkv + 110592;             // 36864
  u16*   pk_c1   = pk_proj + 36864;             // 147456
  u16*   pk_c2   = pk_c1 + 147456;              // 147456
  u8*    wTs8    = (u8*)(pk_c2 + 147456);       // 200704 B (fp8 K=64 frags)
  u16*   spare   = (u16*)(wTs8 + 200704);       // 4816896 u16 (hT alias head)
  u8*    qk8     = (u8*)(spare + 4816896);      // 4816896 B fp8
  u16*   vT      = (u16*)(qk8 + 4816896);       // 2408448 u16
  u16*   attnoT  = vT + 2408448;                // 2408448 u16
  float* x1      = (float*)(attnoT + 2408448);  // 2408448 f
  u16*   x1T     = (u16*)(x1 + 2408448);        // 2408448 u16
  u16*   hT      = spare;  // 9633792 u16 over dead spare+qk8+vT

  bn_stats_k<<<CDIM, 256, 0, stream>>>(x, stats);
  prep3_k<<<946, 256, 0, stream>>>(dm_w, wTs8, proj_w, pk_proj, c1_w, pk_c1,
                                   c2_w, pk_c2);
  fold_pack_k<<<576, 192, 0, stream>>>(qkv_w, qkv_b, bn_gamma, bn_beta, stats,
                                       pk_qkv, b_eff);

  mgemm_k<MG_QKV><<<dim3(98, 9), 256, 0, stream>>>(
      nullptr, pk_qkv, b_eff, nullptr, nullptr, vT, qk8, x, 192);
  attn_fused_k<<<NIMG * 49, 256, 0, stream>>>(qk8, wTs8, vT, dm_b, rel_bias, attnoT);
  mgemm_k<MG_PROJ><<<dim3(98, 3), 256, 0, stream>>>(
      attnoT, pk_proj, proj_b, x1, x1T, nullptr, nullptr, x, 192);
  mgemm_k<MG_GELU><<<dim3(98, 12), 256, 0, stream>>>(
      x1T, pk_c1, c1_b, nullptr, hT, nullptr, nullptr, nullptr, 192);
  mgemm_k<MG_C2><<<dim3(98, 3), 256, 0, stream>>>(
      hT, pk_c2, c2_b, out, nullptr, nullptr, nullptr, x1, 768);
}

// Round 18
// 117.613 us; speedup vs baseline: 1.6307x; 1.0281x over previous
//
#include <hip/hip_runtime.h>
#include <hip/hip_bf16.h>
#include <math.h>

#define CDIM 192
#define NHEADS 6
#define WIN 7
#define KWIN 49
#define BATCH 4
#define PIX 3136      // 56*56
#define NPIX 12544    // BATCH*PIX
#define NIMG 24       // BATCH*NHEADS
#define EPSV 1e-5f

typedef __bf16 bf16x8 __attribute__((ext_vector_type(8)));
typedef float f32x16 __attribute__((ext_vector_type(16)));
typedef unsigned int uint4v __attribute__((ext_vector_type(4)));
typedef unsigned int uint2v __attribute__((ext_vector_type(2)));
typedef int int4x __attribute__((ext_vector_type(4)));
typedef int int8x __attribute__((ext_vector_type(8)));
typedef unsigned short u16;
typedef unsigned char u8;

__device__ inline u8 f32_to_fp8(float v) {
  return (u8)(__builtin_amdgcn_cvt_pk_fp8_f32(v, 0.f, 0, false) & 0xFF);
}

// 8 bf16 (as uint4v) -> 8 fp8 bytes (uint2v)
__device__ inline uint2v bf8_to_fp8x8(uint4v v) {
  const u16* h = (const u16*)&v;
  float f[8];
#pragma unroll
  for (int e = 0; e < 8; e++) {
    unsigned u = ((unsigned)h[e]) << 16;
    f[e] = __builtin_bit_cast(float, u);
  }
  int lo = __builtin_amdgcn_cvt_pk_fp8_f32(f[0], f[1], 0, false);
  lo = __builtin_amdgcn_cvt_pk_fp8_f32(f[2], f[3], lo, true);
  int hi = __builtin_amdgcn_cvt_pk_fp8_f32(f[4], f[5], 0, false);
  hi = __builtin_amdgcn_cvt_pk_fp8_f32(f[6], f[7], hi, true);
  uint2v r = {(unsigned)lo, (unsigned)hi};
  return r;
}

// ---------------- BN stats ---------------------------------------------------
__global__ __launch_bounds__(256) void bn_stats_k(const float* __restrict__ x,
                                                  float* __restrict__ stats) {
  int c = blockIdx.x;
  float s = 0.f, q = 0.f;
  for (int n = threadIdx.x; n < BATCH * PIX; n += 256) {
    int b = n / PIX, p = n - b * PIX;
    float v = x[((size_t)b * CDIM + c) * PIX + p];
    s += v; q += v * v;
  }
  __shared__ float rs[256], rq[256];
  rs[threadIdx.x] = s; rq[threadIdx.x] = q;
  __syncthreads();
  for (int st = 128; st > 0; st >>= 1) {
    if (threadIdx.x < st) { rs[threadIdx.x] += rs[threadIdx.x + st]; rq[threadIdx.x] += rq[threadIdx.x + st]; }
    __syncthreads();
  }
  if (threadIdx.x == 0) {
    float mean = rs[0] / (float)(BATCH * PIX);
    float var = rq[0] / (float)(BATCH * PIX) - mean * mean;
    stats[c] = mean;
    stats[CDIM + c] = rsqrtf(var + EPSV);
  }
}

// ---------------- generic pack helper: W[Cout][Cin] -> frag-major -----------
__device__ inline void pack_one(const float* __restrict__ W, u16* __restrict__ out,
                                int Cin, int t) {
  int lane = t & 63, rest = t >> 6;
  int nK = Cin >> 4;
  int kk = rest % nK, mtg = rest / nK;
  int o = mtg * 32 + (lane & 31), c = kk * 16 + (lane >> 5) * 8;
  const float* src = W + (size_t)o * Cin + c;
  __hip_bfloat16 tmp[8];
#pragma unroll
  for (int e = 0; e < 8; e++) tmp[e] = __float2bfloat16(src[e]);
  *(uint4v*)(out + (size_t)t * 8) = *(uint4v*)tmp;
}

// --- merged prep: qkv fold+pack, dm_w K=64 fp8 pack, proj/c1/c2 packs -------
__global__ __launch_bounds__(256) void prep4_k(
    const float* __restrict__ qkv_w, const float* __restrict__ qkv_b,
    const float* __restrict__ gamma, const float* __restrict__ beta,
    const float* __restrict__ stats, u16* __restrict__ pk_qkv,
    float* __restrict__ b_eff,
    const float* __restrict__ dm_w, u8* __restrict__ wTs8,
    const float* __restrict__ proj_w, u16* __restrict__ pk_proj,
    const float* __restrict__ c1_w, u16* __restrict__ pk_c1,
    const float* __restrict__ c2_w, u16* __restrict__ pk_c2) {
  __shared__ float r[CDIM];
  int bid = blockIdx.x, tid = threadIdx.x;
  if (bid < 576) {
    int o = bid;
    if (tid < CDIM) {
      int c = tid;
      float alpha = gamma[c] * stats[CDIM + c];
      float shift = beta[c] - stats[c] * alpha;
      float w = qkv_w[o * CDIM + c];
      float scale = (o < CDIM) ? 0.17677669529663687f : 1.f;
      int t8 = ((((o >> 5) * 12 + (c >> 4)) * 64 + (((c >> 3) & 1) * 32 + (o & 31))) << 3) + (c & 7);
      ((__hip_bfloat16*)pk_qkv)[t8] = __float2bfloat16(w * alpha * scale);
      r[c] = w * shift;
    }
    __syncthreads();
    if (tid == 0) {
      float s = 0.f;
      for (int i = 0; i < CDIM; i++) s += r[i];
      float scale = (o < CDIM) ? 0.17677669529663687f : 1.f;
      b_eff[o] = (qkv_b[o] + s) * scale;
    }
  } else if (bid < 1360) {
    int idx = (bid - 576) * 256 + tid;   // < 200704
    int e = idx & 31;
    int tmp = idx >> 5;
    int lane = tmp & 63; tmp >>= 6;
    int Mt = tmp & 1;
    int tap = tmp >> 1;                  // 0..48
    int ko = Mt * 32 + (lane & 31);
    int ci = (lane >> 5) * 32 + e;
    float v = (ko < KWIN) ? dm_w[(size_t)ko * 3136 + ci * 49 + tap] : 0.f;
    wTs8[idx] = f32_to_fp8(v);
  } else if (bid < 1378) {
    int t = (bid - 1360) * 256 + tid;
    if (t < 4608) pack_one(proj_w, pk_proj, 192, t);
  } else if (bid < 1450) {
    int t = (bid - 1378) * 256 + tid;
    if (t < 18432) pack_one(c1_w, pk_c1, 192, t);
  } else {
    int t = (bid - 1450) * 256 + tid;
    if (t < 18432) pack_one(c2_w, pk_c2, 768, t);
  }
}

// ------- MFMA GEMM: 128px x 64o tile, double-buffered async staging ---------
#define MG_QKV 0
#define MG_PROJ 1
#define MG_GELU 2
#define MG_C2 3
#define MG2S 1032   // B plane stride u16 (128*8 + 8 pad)

template <int EPI>
__global__ __launch_bounds__(256, 3) void mgemm_k(
    const u16* __restrict__ Bm, const u16* __restrict__ Apk,
    const float* __restrict__ bias,
    float* __restrict__ outF, u16* __restrict__ outT, u16* __restrict__ outT2,
    u8* __restrict__ outQK8,
    const float* __restrict__ extra, int Cin) {
  __shared__ __align__(16) u16 Bs[2][8 * MG2S];  // 2 x 16.5 KB
  __shared__ __align__(16) u16 As[2][4096];      // 2 x 8 KB
  int tid = threadIdx.x;
  int lane = tid & 63, wid = tid >> 6;
  int hi = lane >> 5, ln31 = lane & 31;
  int p0 = blockIdx.x * 128;
  int o0 = blockIdx.y * 64;
  int nK = Cin >> 4;
  int nKC = Cin >> 6;
  f32x16 acc[2];
#pragma unroll
  for (int mt = 0; mt < 2; mt++)
#pragma unroll
    for (int i = 0; i < 16; i++) acc[mt][i] = 0.f;

  uint4v bReg[4], aReg[2];

  auto loadC = [&](int kc) {
    int cc = kc * 64;
    if (EPI == MG_QKV) {
      int px = tid & 127, gh = tid >> 7;
      unsigned gp = p0 + px;
      unsigned bb = gp / PIX, pp = gp - bb * PIX;
#pragma unroll
      for (int j = 0; j < 4; j++) {
        int g = gh * 4 + j;
        const float* xb = extra + ((size_t)bb * CDIM + cc + g * 8) * PIX + pp;
        __hip_bfloat16 t8[8];
#pragma unroll
        for (int e = 0; e < 8; e++) t8[e] = __float2bfloat16(xb[(size_t)e * PIX]);
        bReg[j] = *(uint4v*)t8;
      }
    } else {
#pragma unroll
      for (int i = 0; i < 4; i++) {
        int idx = i * 256 + tid;
        int px = idx >> 3, g = idx & 7;
        bReg[i] = *(const uint4v*)(Bm + (size_t)(p0 + px) * Cin + cc + g * 8);
      }
    }
#pragma unroll
    for (int i = 0; i < 2; i++) {
      int idx = i * 256 + tid;
      int frag = idx >> 6, l64 = idx & 63;
      int mt = frag >> 2, ks = frag & 3;
      aReg[i] = *(const uint4v*)(Apk +
          (size_t)(((o0 >> 5) + mt) * nK + kc * 4 + ks) * 512 + l64 * 8);
    }
  };
  auto storeC = [&](int buf) {
    if (EPI == MG_QKV) {
      int px = tid & 127, gh = tid >> 7;
#pragma unroll
      for (int j = 0; j < 4; j++)
        *(uint4v*)&Bs[buf][(gh * 4 + j) * MG2S + px * 8] = bReg[j];
    } else {
#pragma unroll
      for (int i = 0; i < 4; i++) {
        int idx = i * 256 + tid;
        int px = idx >> 3, g = idx & 7;
        *(uint4v*)&Bs[buf][g * MG2S + px * 8] = bReg[i];
      }
    }
#pragma unroll
    for (int i = 0; i < 2; i++) {
      int idx = i * 256 + tid;
      int frag = idx >> 6, l64 = idx & 63;
      *(uint4v*)&As[buf][frag * 512 + l64 * 8] = aReg[i];
    }
  };

  loadC(0);
  storeC(0);
  __syncthreads();
  int pxw = wid * 32 + ln31;
  for (int kc = 0; kc < nKC; kc++) {
    int cur = kc & 1;
    bool more = (kc + 1 < nKC);
    if (more) loadC(kc + 1);            // global loads overlap MFMAs below
#pragma unroll
    for (int ks = 0; ks < 4; ks++) {
      int g = ks * 2 + hi;
      bf16x8 b  = *(const bf16x8*)&Bs[cur][g * MG2S + pxw * 8];
      bf16x8 a0 = *(const bf16x8*)&As[cur][ks * 512 + lane * 8];
      bf16x8 a1 = *(const bf16x8*)&As[cur][(4 + ks) * 512 + lane * 8];
      acc[0] = __builtin_amdgcn_mfma_f32_32x32x16_bf16(a0, b, acc[0], 0, 0, 0);
      acc[1] = __builtin_amdgcn_mfma_f32_32x32x16_bf16(a1, b, acc[1], 0, 0, 0);
    }
    if (more) storeC(cur ^ 1);          // write other buffer (no race)
    __syncthreads();
  }

  // ---- epilogue ----
  if (EPI == MG_C2) {
#pragma unroll
    for (int mt = 0; mt < 2; mt++)
#pragma unroll
      for (int r = 0; r < 16; r++) {
        int o = o0 + mt * 32 + (r & 3) + 8 * (r >> 2) + 4 * hi;
        float bv = bias[o];
        unsigned gp = p0 + pxw;
        unsigned bb = gp / PIX, pp = gp - bb * PIX;
        size_t oi = ((size_t)bb * CDIM + o) * PIX + pp;
        outF[oi] = acc[mt][r] + bv + extra[oi];
      }
  } else {
    u16* scratch = (u16*)Bs;            // 128 rows x 64 o x 2B = 16 KB
#pragma unroll
    for (int mt = 0; mt < 2; mt++)
#pragma unroll
      for (int r = 0; r < 16; r++) {
        int o_loc = mt * 32 + (r & 3) + 8 * (r >> 2) + 4 * hi;
        int o = o0 + o_loc;
        float bv = bias[o];
        int p_loc = pxw;
        float val = acc[mt][r] + bv;
        if (EPI == MG_PROJ) {
          unsigned gp = p0 + p_loc;
          unsigned bb = gp / PIX, pp = gp - bb * PIX;
          size_t oi = ((size_t)bb * CDIM + o) * PIX + pp;
          val += extra[oi];
          outF[oi] = val;
        }
        if (EPI == MG_GELU)
          val = 0.5f * val * (1.f + erff(val * 0.70710678118654752f));
        *(__hip_bfloat16*)&scratch[p_loc * 64 + (((o_loc >> 3) ^ (p_loc & 7)) << 3) + (o_loc & 7)] =
            __float2bfloat16(val);
      }
    __syncthreads();
    int prow = tid >> 1, half = tid & 1;
    int psw = prow & 7;
    uint4v r4[4];
#pragma unroll
    for (int j = 0; j < 4; j++)
      r4[j] = *(const uint4v*)&scratch[prow * 64 + ((((half << 2) + j) ^ psw) << 3)];
    unsigned gp = p0 + prow;
    if (EPI == MG_QKV) {
      unsigned bb = gp / PIX, pp = gp - bb * PIX;
      int s = o0 / 192;               // 0=q, 1=k, 2=v
      int h0 = ((o0 - s * 192) >> 5) + half;
      if (s < 2) {
        uint2v c0 = bf8_to_fp8x8(r4[0]), c1 = bf8_to_fp8x8(r4[1]);
        uint2v c2 = bf8_to_fp8x8(r4[2]), c3 = bf8_to_fp8x8(r4[3]);
        uint4v w0 = {c0[0], c0[1], c1[0], c1[1]};
        uint4v w1 = {c2[0], c2[1], c3[0], c3[1]};
        u8* d = outQK8 + ((size_t)(bb * NHEADS + h0) * PIX + pp) * 64 + s * 32;
        *(uint4v*)(d) = w0; *(uint4v*)(d + 16) = w1;
      } else {                        // v -> vT[img][pix][32] bf16
        u16* d = outT2 + ((size_t)(bb * NHEADS + h0) * PIX + pp) * 32;
        *(uint4v*)(d) = r4[0]; *(uint4v*)(d + 8) = r4[1];
        *(uint4v*)(d + 16) = r4[2]; *(uint4v*)(d + 24) = r4[3];
      }
    } else if (EPI == MG_PROJ) {
      u16* d = outT + (size_t)gp * CDIM + o0 + half * 32;
#pragma unroll
      for (int j = 0; j < 4; j++) *(uint4v*)(d + j * 8) = r4[j];
    } else {  // GELU -> hT [gp][768]
      u16* d = outT + (size_t)gp * 768 + o0 + half * 32;
#pragma unroll
      for (int j = 0; j < 4; j++) *(uint4v*)(d + j * 8) = r4[j];
    }
  }
}

// ------ 7x7 attn conv (MX-scaled fp8 K=64 MFMA) + fused softmax/PV ----------
// V-patch loads issued into regs BEFORE the MFMA loop (T14 async-split).
#define VPS 40
#define SMS 65
#define DIV7(t) (((t) * 9363) >> 16)
#define LPOF(t) ((t) + 7 * DIV7(t))

__global__ __launch_bounds__(256, 5) void attn_fused_k(
    const u8* __restrict__ qk8, const u8* __restrict__ wTs8,
    const u16* __restrict__ vT,
    const float* __restrict__ dm_b, const float* __restrict__ rel_bias,
    u16* __restrict__ attnoT) {
  __shared__ __align__(16) u16 shraw[14216];   // 28432 B -> 5 blocks/CU
  u8* patchB = (u8*)shraw;                     // phase1: 196 x 64B = 12.5 KB
  int img = blockIdx.x / 49;
  int tile = blockIdx.x % 49;
  int y0 = (tile / 7) * 8, x0 = (tile % 7) * 8;
  int tid = threadIdx.x;
  const u8* qimg = qk8 + (size_t)img * PIX * 64;
  for (int idx = tid; idx < 784; idx += 256) {
    int lp = idx >> 2, slot = idx & 3;
    int r = lp / 14, c = lp - r * 14;
    int gy = y0 - 3 + r, gx = x0 - 3 + c;
    uint4v val = {0u, 0u, 0u, 0u};
    if ((unsigned)gy < 56u && (unsigned)gx < 56u)
      val = *(const uint4v*)(qimg + (size_t)(gy * 56 + gx) * 64 + slot * 16);
    *(uint4v*)&patchB[lp * 64 + ((slot ^ ((lp >> 1) & 3)) << 4)] = val;
  }
  __syncthreads();

  // T14: issue V-patch global loads now; LDS-write after the MFMA phase.
  const u16* vbase = vT + (size_t)img * PIX * 32;
  uint4v vreg[4];
#pragma unroll
  for (int s = 0; s < 4; s++) {
    int idx = s * 256 + tid;
    uint4v val = {0u, 0u, 0u, 0u};
    if (s < 3 || idx < 784) {
      int g = idx & 3, lp = idx >> 2;
      int r = lp / 14, c = lp - r * 14;
      int gy = y0 - 3 + r, gx = x0 - 3 + c;
      if ((unsigned)gy < 56u && (unsigned)gx < 56u)
        val = *(const uint4v*)(vbase + (size_t)(gy * 56 + gx) * 32 + g * 8);
    }
    vreg[s] = val;
  }

  int lane = tid & 63, wid = tid >> 6;
  int Mtile = wid & 1, Ntile = wid >> 1;
  int n = lane & 31, hi = lane >> 5;
  int py = Ntile * 4 + (n >> 3), px = n & 7;
  int lpb = py * 14 + px;
  f32x16 acc0, acc1;
#pragma unroll
  for (int i = 0; i < 16; i++) { acc0[i] = 0.f; acc1[i] = 0.f; }

  const u8* Aw = wTs8 + Mtile * 2048 + lane * 32;
#pragma unroll
  for (int tap = 0; tap < KWIN; tap++) {
    int lp_ = lpb + LPOF(tap);
    const int4x* ap = (const int4x*)(Aw + tap * 4096);
    int4x alo = ap[0], ahi = ap[1];
    int sw = (lp_ >> 1) & 3;
    int4x blo = *(const int4x*)&patchB[lp_ * 64 + (((2 * hi) ^ sw) << 4)];
    int4x bhi = *(const int4x*)&patchB[lp_ * 64 + (((2 * hi + 1) ^ sw) << 4)];
    int8x a = __builtin_shufflevector(alo, ahi, 0, 1, 2, 3, 4, 5, 6, 7);
    int8x b = __builtin_shufflevector(blo, bhi, 0, 1, 2, 3, 4, 5, 6, 7);
    if (tap & 1)
      acc1 = __builtin_amdgcn_mfma_scale_f32_32x32x64_f8f6f4(
          a, b, acc1, 0, 0, 0, 127, 0, 127);
    else
      acc0 = __builtin_amdgcn_mfma_scale_f32_32x32x64_f8f6f4(
          a, b, acc0, 0, 0, 0, 127, 0, 127);
  }

  // ---- fused tail: logits -> smx[49][SMS], vreg -> vp, softmax, PV ---------
  __syncthreads();
  float* smx = (float*)shraw;            // 49 x 65 x 4 = 12740 B
  u16* vp = shraw + 6376;                // [196 pix][VPS] bf16 (15680 B)
  int head = img % NHEADS;
#pragma unroll
  for (int r = 0; r < 16; r++) {
    int ko = Mtile * 32 + (r & 3) + 8 * (r >> 2) + 4 * hi;
    if (ko < KWIN)
      smx[ko * SMS + Ntile * 32 + n] =
          acc0[r] + acc1[r] + dm_b[ko] + rel_bias[ko * NHEADS + head];
  }
#pragma unroll
  for (int s = 0; s < 4; s++) {
    int idx = s * 256 + tid;
    if (s < 3 || idx < 784) {
      int g = idx & 3, lp = idx >> 2;
      *(uint4v*)&vp[lp * VPS + g * 8] = vreg[s];
    }
  }
  __syncthreads();
  {
    int pxs = tid >> 2, q4 = tid & 3;
    int k0 = q4 * 13;
    int k1 = (q4 == 3) ? KWIN : k0 + 13;
    float m = -1e30f;
    for (int k = k0; k < k1; k++) m = fmaxf(m, smx[k * SMS + pxs]);
    m = fmaxf(m, __shfl_xor(m, 1, 64));
    m = fmaxf(m, __shfl_xor(m, 2, 64));
    float ssum = 0.f;
    for (int k = k0; k < k1; k++) {
      float e = __expf(smx[k * SMS + pxs] - m);
      smx[k * SMS + pxs] = e;
      ssum += e;
    }
    ssum += __shfl_xor(ssum, 1, 64);
    ssum += __shfl_xor(ssum, 2, 64);
    float inv = 1.f / ssum;
    for (int k = k0; k < k1; k++) smx[k * SMS + pxs] *= inv;
  }
  __syncthreads();
  int pxl = tid & 63, co = tid >> 6;
  int pyy = pxl >> 3, pxx = pxl & 7;
  float o8[8] = {0.f, 0.f, 0.f, 0.f, 0.f, 0.f, 0.f, 0.f};
#pragma unroll
  for (int kh = 0; kh < 7; kh++) {
#pragma unroll
    for (int kw = 0; kw < 7; kw++) {
      float p = smx[(kh * 7 + kw) * SMS + pxl];
      bf16x8 v = *(const bf16x8*)&vp[((pyy + kh) * 14 + pxx + kw) * VPS + co * 8];
#pragma unroll
      for (int j = 0; j < 8; j++) o8[j] += p * (float)v[j];
    }
  }
  int gp = (y0 + pyy) * 56 + x0 + pxx;
  int b = img / NHEADS;
  __hip_bfloat16 ob[8];
#pragma unroll
  for (int j = 0; j < 8; j++) ob[j] = __float2bfloat16(o8[j]);
  *(uint4v*)(attnoT + ((size_t)b * PIX + gp) * CDIM + head * 32 + co * 8) = *(uint4v*)ob;
}

// ---------------- launch ----------------------------------------------------
extern "C" void kernel_launch(void* const* d_in, const int* in_sizes, int n_in,
                              void* d_out, int out_size, void* d_ws, size_t ws_size,
                              hipStream_t stream) {
  const float* x        = (const float*)d_in[0];
  const float* bn_gamma = (const float*)d_in[1];
  const float* bn_beta  = (const float*)d_in[2];
  const float* qkv_w    = (const float*)d_in[3];
  const float* qkv_b    = (const float*)d_in[4];
  const float* dm_w     = (const float*)d_in[5];
  const float* dm_b     = (const float*)d_in[6];
  const float* rel_bias = (const float*)d_in[7];
  const float* proj_w   = (const float*)d_in[8];
  const float* proj_b   = (const float*)d_in[9];
  const float* c1_w     = (const float*)d_in[10];
  const float* c1_b     = (const float*)d_in[11];
  const float* c2_w     = (const float*)d_in[12];
  const float* c2_b     = (const float*)d_in[13];
  float* out = (float*)d_out;
  float* ws  = (float*)d_ws;

  float* stats   = ws;                          // 384 f
  float* b_eff   = stats + 384;                 // 576 f
  u16*   pk_qkv  = (u16*)(b_eff + 576);         // 110592 u16
  u16*   pk_proj = pk_qkv + 110592;             // 36864
  u16*   pk_c1   = pk_proj + 36864;             // 147456
  u16*   pk_c2   = pk_c1 + 147456;              // 147456
  u8*    wTs8    = (u8*)(pk_c2 + 147456);       // 200704 B (fp8 K=64 frags)
  u16*   spare   = (u16*)(wTs8 + 200704);       // 4816896 u16 (hT alias head)
  u8*    qk8     = (u8*)(spare + 4816896);      // 4816896 B fp8
  u16*   vT      = (u16*)(qk8 + 4816896);       // 2408448 u16
  u16*   attnoT  = vT + 2408448;                // 2408448 u16
  float* x1      = (float*)(attnoT + 2408448);  // 2408448 f
  u16*   x1T     = (u16*)(x1 + 2408448);        // 2408448 u16
  u16*   hT      = spare;  // 9633792 u16 over dead spare+qk8+vT

  bn_stats_k<<<CDIM, 256, 0, stream>>>(x, stats);
  prep4_k<<<1522, 256, 0, stream>>>(qkv_w, qkv_b, bn_gamma, bn_beta, stats,
                                    pk_qkv, b_eff, dm_w, wTs8,
                                    proj_w, pk_proj, c1_w, pk_c1, c2_w, pk_c2);

  mgemm_k<MG_QKV><<<dim3(98, 9), 256, 0, stream>>>(
      nullptr, pk_qkv, b_eff, nullptr, nullptr, vT, qk8, x, 192);
  attn_fused_k<<<NIMG * 49, 256, 0, stream>>>(qk8, wTs8, vT, dm_b, rel_bias, attnoT);
  mgemm_k<MG_PROJ><<<dim3(98, 3), 256, 0, stream>>>(
      attnoT, pk_proj, proj_b, x1, x1T, nullptr, nullptr, x, 192);
  mgemm_k<MG_GELU><<<dim3(98, 12), 256, 0, stream>>>(
      x1T, pk_c1, c1_b, nullptr, hT, nullptr, nullptr, nullptr, 192);
  mgemm_k<MG_C2><<<dim3(98, 3), 256, 0, stream>>>(
      hT, pk_c2, c2_b, out, nullptr, nullptr, nullptr, x1, 768);
}

// Round 19
// 97.953 us; speedup vs baseline: 1.9580x; 1.2007x over previous
//
#include <hip/hip_runtime.h>
#include <hip/hip_bf16.h>
#include <math.h>

#define CDIM 192
#define NHEADS 6
#define WIN 7
#define KWIN 49
#define BATCH 4
#define PIX 3136      // 56*56
#define NPIX 12544    // BATCH*PIX
#define NIMG 24       // BATCH*NHEADS
#define EPSV 1e-5f

typedef __bf16 bf16x8 __attribute__((ext_vector_type(8)));
typedef float f32x16 __attribute__((ext_vector_type(16)));
typedef unsigned int uint4v __attribute__((ext_vector_type(4)));
typedef unsigned int uint2v __attribute__((ext_vector_type(2)));
typedef int int4x __attribute__((ext_vector_type(4)));
typedef int int8x __attribute__((ext_vector_type(8)));
typedef unsigned short u16;
typedef unsigned char u8;

__device__ inline u8 f32_to_fp8(float v) {
  return (u8)(__builtin_amdgcn_cvt_pk_fp8_f32(v, 0.f, 0, false) & 0xFF);
}

// 8 bf16 (as uint4v) -> 8 fp8 bytes
__device__ inline uint2v bf8_to_fp8x8(uint4v v) {
  const u16* h = (const u16*)&v;
  float f[8];
#pragma unroll
  for (int e = 0; e < 8; e++) {
    unsigned u = ((unsigned)h[e]) << 16;
    f[e] = __builtin_bit_cast(float, u);
  }
  int lo = __builtin_amdgcn_cvt_pk_fp8_f32(f[0], f[1], 0, false);
  lo = __builtin_amdgcn_cvt_pk_fp8_f32(f[2], f[3], lo, true);
  int hi = __builtin_amdgcn_cvt_pk_fp8_f32(f[4], f[5], 0, false);
  hi = __builtin_amdgcn_cvt_pk_fp8_f32(f[6], f[7], hi, true);
  uint2v r = {(unsigned)lo, (unsigned)hi};
  return r;
}

// 8 f32 -> 8 fp8 bytes
__device__ inline uint2v f32x8_to_fp8(const float* f) {
  int lo = __builtin_amdgcn_cvt_pk_fp8_f32(f[0], f[1], 0, false);
  lo = __builtin_amdgcn_cvt_pk_fp8_f32(f[2], f[3], lo, true);
  int hi = __builtin_amdgcn_cvt_pk_fp8_f32(f[4], f[5], 0, false);
  hi = __builtin_amdgcn_cvt_pk_fp8_f32(f[6], f[7], hi, true);
  uint2v r = {(unsigned)lo, (unsigned)hi};
  return r;
}

// ---------------- BN stats ---------------------------------------------------
__global__ __launch_bounds__(256) void bn_stats_k(const float* __restrict__ x,
                                                  float* __restrict__ stats) {
  int c = blockIdx.x;
  float s = 0.f, q = 0.f;
  for (int n = threadIdx.x; n < BATCH * PIX; n += 256) {
    int b = n / PIX, p = n - b * PIX;
    float v = x[((size_t)b * CDIM + c) * PIX + p];
    s += v; q += v * v;
  }
  __shared__ float rs[256], rq[256];
  rs[threadIdx.x] = s; rq[threadIdx.x] = q;
  __syncthreads();
  for (int st = 128; st > 0; st >>= 1) {
    if (threadIdx.x < st) { rs[threadIdx.x] += rs[threadIdx.x + st]; rq[threadIdx.x] += rq[threadIdx.x + st]; }
    __syncthreads();
  }
  if (threadIdx.x == 0) {
    float mean = rs[0] / (float)(BATCH * PIX);
    float var = rq[0] / (float)(BATCH * PIX) - mean * mean;
    stats[c] = mean;
    stats[CDIM + c] = rsqrtf(var + EPSV);
  }
}

// -------- fp8 K=64 frag pack: W[Cout][Cin] -> [oT][kc][lane][32B] -----------
__device__ inline void pack8_one(const float* __restrict__ W, u8* __restrict__ out,
                                 int Cin, int t, int total) {
  if (t >= total) return;
  int lane = t & 63, rest = t >> 6;
  int nKC = Cin >> 6;
  int kc = rest % nKC, oT = rest / nKC;
  int o = oT * 32 + (lane & 31), c = kc * 64 + (lane >> 5) * 32;
  const float* src = W + (size_t)o * Cin + c;
  u8 tmp[32];
#pragma unroll
  for (int e = 0; e < 32; e++) tmp[e] = f32_to_fp8(src[e]);
  *(uint4v*)(out + (size_t)t * 32) = *(uint4v*)tmp;
  *(uint4v*)(out + (size_t)t * 32 + 16) = *(uint4v*)(tmp + 16);
}

// --- merged prep: qkv fold->fp8 frags, dm_w fp8, proj/c1/c2 fp8, xT8 --------
__global__ __launch_bounds__(256) void prep5_k(
    const float* __restrict__ qkv_w, const float* __restrict__ qkv_b,
    const float* __restrict__ gamma, const float* __restrict__ beta,
    const float* __restrict__ stats, u8* __restrict__ pk_qkv8,
    float* __restrict__ b_eff,
    const float* __restrict__ dm_w, u8* __restrict__ wTs8,
    const float* __restrict__ proj_w, u8* __restrict__ pk_proj8,
    const float* __restrict__ c1_w, u8* __restrict__ pk_c18,
    const float* __restrict__ c2_w, u8* __restrict__ pk_c28,
    const float* __restrict__ x, u8* __restrict__ xT8) {
  __shared__ float shf[64 * 33];
  int bid = blockIdx.x, tid = threadIdx.x;
  if (bid < 576) {
    int o = bid;
    float* r = shf;
    if (tid < CDIM) {
      int c = tid;
      float alpha = gamma[c] * stats[CDIM + c];
      float shift = beta[c] - stats[c] * alpha;
      float w = qkv_w[o * CDIM + c];
      float scale = (o < CDIM) ? 0.17677669529663687f : 1.f;
      // fp8 K=64 frag: byte ((oT*3+kc)*64 + khalf*32 + ko)*32 + (c&31)
      int bidx = (((o >> 5) * 3 + (c >> 6)) * 64 + (((c >> 5) & 1) * 32 + (o & 31))) * 32 + (c & 31);
      pk_qkv8[bidx] = f32_to_fp8(w * alpha * scale);
      r[c] = w * shift;
    }
    __syncthreads();
    if (tid == 0) {
      float s = 0.f;
      for (int i = 0; i < CDIM; i++) s += r[i];
      float scale = (o < CDIM) ? 0.17677669529663687f : 1.f;
      b_eff[o] = (qkv_b[o] + s) * scale;
    }
  } else if (bid < 1360) {
    int idx = (bid - 576) * 256 + tid;   // < 200704
    int e = idx & 31;
    int tmp = idx >> 5;
    int lane = tmp & 63; tmp >>= 6;
    int Mt = tmp & 1;
    int tap = tmp >> 1;                  // 0..48
    int ko = Mt * 32 + (lane & 31);
    int ci = (lane >> 5) * 32 + e;
    float v = (ko < KWIN) ? dm_w[(size_t)ko * 3136 + ci * 49 + tap] : 0.f;
    wTs8[idx] = f32_to_fp8(v);
  } else if (bid < 1365) {
    pack8_one(proj_w, pk_proj8, 192, (bid - 1360) * 256 + tid, 1152);
  } else if (bid < 1383) {
    pack8_one(c1_w, pk_c18, 192, (bid - 1365) * 256 + tid, 4608);
  } else if (bid < 1401) {
    pack8_one(c2_w, pk_c28, 768, (bid - 1383) * 256 + tid, 4608);
  } else {
    int t = bid - 1401;                 // [0,1176): x -> xT8 transpose + fp8
    int bx = t % 196, by = t / 196;
    int bb = bx / 49;
    int p0 = (bx % 49) * 64;
    int c0 = by * 32;
    float (*Ls)[33] = (float(*)[33])shf;
    int j = tid & 63;
#pragma unroll
    for (int it = 0; it < 8; it++) {
      int c = it * 4 + (tid >> 6);
      Ls[j][c] = x[((size_t)bb * CDIM + c0 + c) * PIX + p0 + j];
    }
    __syncthreads();
    int jr = tid >> 2, tt = tid & 3;
    float f[8];
#pragma unroll
    for (int u = 0; u < 8; u++) f[u] = Ls[jr][tt * 8 + u];
    uint2v w = f32x8_to_fp8(f);
    *(uint2v*)(xT8 + (size_t)(bb * PIX + p0 + jr) * CDIM + c0 + tt * 8) = w;
  }
}

// ----- MX-fp8 MFMA GEMM: 128px x 64o, K=64 chunks, dbuf async staging -------
// Inputs px-major fp8 [gp][Cin]. Per chunk per wave: 2 MX MFMAs + pure-copy
// staging (no in-loop conversion). Weights pre-packed fp8 K=64 frags.
#define MG_QKV 0
#define MG_PROJ 1
#define MG_GELU 2
#define MG_C2 3

template <int EPI>
__global__ __launch_bounds__(256, 4) void mgemm8_k(
    const u8* __restrict__ Bm8, const u8* __restrict__ Apk8,
    const float* __restrict__ bias,
    float* __restrict__ outF, u8* __restrict__ outT8, u16* __restrict__ outT2,
    u8* __restrict__ outQK8,
    const float* __restrict__ extra, int Cin) {
  __shared__ __align__(16) u8 Bs8[2][8192];   // [px 128][64B]
  __shared__ __align__(16) u8 As8[2][4096];   // [mt 2][lane 64][32B]
  int tid = threadIdx.x;
  int lane = tid & 63, wid = tid >> 6;
  int hi = lane >> 5, ln31 = lane & 31;
  int p0 = blockIdx.x * 128;
  int o0 = blockIdx.y * 64;
  int nKC = Cin >> 6;
  f32x16 acc[2];
#pragma unroll
  for (int mt = 0; mt < 2; mt++)
#pragma unroll
    for (int i = 0; i < 16; i++) acc[mt][i] = 0.f;

  uint4v bReg[2], aReg;
  auto loadC = [&](int kc) {
    int cc = kc * 64;
#pragma unroll
    for (int i = 0; i < 2; i++) {
      int idx = i * 256 + tid;
      int px = idx >> 2, slot = idx & 3;
      bReg[i] = *(const uint4v*)(Bm8 + (size_t)(p0 + px) * Cin + cc + slot * 16);
    }
    int frag = tid >> 7, off = (tid & 127) * 16;
    aReg = *(const uint4v*)(Apk8 + (size_t)(((o0 >> 5) + frag) * nKC + kc) * 2048 + off);
  };
  auto storeC = [&](int buf) {
#pragma unroll
    for (int i = 0; i < 2; i++) {
      int idx = i * 256 + tid;
      int px = idx >> 2, slot = idx & 3;
      *(uint4v*)&Bs8[buf][px * 64 + ((slot ^ (px & 3)) << 4)] = bReg[i];
    }
    int frag = tid >> 7, off = (tid & 127) * 16;
    *(uint4v*)&As8[buf][frag * 2048 + off] = aReg;
  };

  loadC(0);
  storeC(0);
  __syncthreads();
  int pxw = wid * 32 + ln31;
  int swb = pxw & 3;
  for (int kc = 0; kc < nKC; kc++) {
    int cur = kc & 1;
    bool more = (kc + 1 < nKC);
    if (more) loadC(kc + 1);            // global loads overlap MFMAs
    int4x a0lo = *(const int4x*)&As8[cur][lane * 32];
    int4x a0hi = *(const int4x*)&As8[cur][lane * 32 + 16];
    int4x a1lo = *(const int4x*)&As8[cur][2048 + lane * 32];
    int4x a1hi = *(const int4x*)&As8[cur][2048 + lane * 32 + 16];
    int4x blo = *(const int4x*)&Bs8[cur][pxw * 64 + (((2 * hi) ^ swb) << 4)];
    int4x bhi = *(const int4x*)&Bs8[cur][pxw * 64 + (((2 * hi + 1) ^ swb) << 4)];
    int8x a0 = __builtin_shufflevector(a0lo, a0hi, 0, 1, 2, 3, 4, 5, 6, 7);
    int8x a1 = __builtin_shufflevector(a1lo, a1hi, 0, 1, 2, 3, 4, 5, 6, 7);
    int8x b = __builtin_shufflevector(blo, bhi, 0, 1, 2, 3, 4, 5, 6, 7);
    acc[0] = __builtin_amdgcn_mfma_scale_f32_32x32x64_f8f6f4(
        a0, b, acc[0], 0, 0, 0, 127, 0, 127);
    acc[1] = __builtin_amdgcn_mfma_scale_f32_32x32x64_f8f6f4(
        a1, b, acc[1], 0, 0, 0, 127, 0, 127);
    if (more) storeC(cur ^ 1);
    __syncthreads();
  }

  // ---- epilogue ----
  if (EPI == MG_C2) {
#pragma unroll
    for (int mt = 0; mt < 2; mt++)
#pragma unroll
      for (int r = 0; r < 16; r++) {
        int o = o0 + mt * 32 + (r & 3) + 8 * (r >> 2) + 4 * hi;
        float bv = bias[o];
        unsigned gp = p0 + pxw;
        unsigned bb = gp / PIX, pp = gp - bb * PIX;
        size_t oi = ((size_t)bb * CDIM + o) * PIX + pp;
        outF[oi] = acc[mt][r] + bv + extra[oi];
      }
  } else {
    u16* scratch = (u16*)Bs8;           // 128 rows x 64 o x 2B = 16 KB
#pragma unroll
    for (int mt = 0; mt < 2; mt++)
#pragma unroll
      for (int r = 0; r < 16; r++) {
        int o_loc = mt * 32 + (r & 3) + 8 * (r >> 2) + 4 * hi;
        int o = o0 + o_loc;
        float bv = bias[o];
        int p_loc = pxw;
        float val = acc[mt][r] + bv;
        if (EPI == MG_PROJ) {
          unsigned gp = p0 + p_loc;
          unsigned bb = gp / PIX, pp = gp - bb * PIX;
          size_t oi = ((size_t)bb * CDIM + o) * PIX + pp;
          val += extra[oi];
          outF[oi] = val;               // x1 fp32 (residual included)
        }
        if (EPI == MG_GELU)
          val = 0.5f * val * (1.f + erff(val * 0.70710678118654752f));
        *(__hip_bfloat16*)&scratch[p_loc * 64 + (((o_loc >> 3) ^ (p_loc & 7)) << 3) + (o_loc & 7)] =
            __float2bfloat16(val);
      }
    __syncthreads();
    int prow = tid >> 1, half = tid & 1;
    int psw = prow & 7;
    uint4v r4[4];
#pragma unroll
    for (int j = 0; j < 4; j++)
      r4[j] = *(const uint4v*)&scratch[prow * 64 + ((((half << 2) + j) ^ psw) << 3)];
    unsigned gp = p0 + prow;
    if (EPI == MG_QKV) {
      unsigned bb = gp / PIX, pp = gp - bb * PIX;
      int s = o0 / 192;               // 0=q, 1=k, 2=v
      int h0 = ((o0 - s * 192) >> 5) + half;
      if (s < 2) {
        uint2v c0 = bf8_to_fp8x8(r4[0]), c1 = bf8_to_fp8x8(r4[1]);
        uint2v c2 = bf8_to_fp8x8(r4[2]), c3 = bf8_to_fp8x8(r4[3]);
        uint4v w0 = {c0[0], c0[1], c1[0], c1[1]};
        uint4v w1 = {c2[0], c2[1], c3[0], c3[1]};
        u8* d = outQK8 + ((size_t)(bb * NHEADS + h0) * PIX + pp) * 64 + s * 32;
        *(uint4v*)(d) = w0; *(uint4v*)(d + 16) = w1;
      } else {                        // v -> vT[img][pix][32] bf16
        u16* d = outT2 + ((size_t)(bb * NHEADS + h0) * PIX + pp) * 32;
        *(uint4v*)(d) = r4[0]; *(uint4v*)(d + 8) = r4[1];
        *(uint4v*)(d + 16) = r4[2]; *(uint4v*)(d + 24) = r4[3];
      }
    } else {  // PROJ -> x1T8 [gp][192] fp8; GELU -> hT8 [gp][768] fp8
      uint2v c0 = bf8_to_fp8x8(r4[0]), c1 = bf8_to_fp8x8(r4[1]);
      uint2v c2 = bf8_to_fp8x8(r4[2]), c3 = bf8_to_fp8x8(r4[3]);
      uint4v w0 = {c0[0], c0[1], c1[0], c1[1]};
      uint4v w1 = {c2[0], c2[1], c3[0], c3[1]};
      int stride = (EPI == MG_PROJ) ? CDIM : 768;
      u8* d = outT8 + (size_t)gp * stride + o0 + half * 32;
      *(uint4v*)(d) = w0; *(uint4v*)(d + 16) = w1;
    }
  }
}

// ------ 7x7 attn conv (MX-scaled fp8 K=64 MFMA) + fused softmax/PV ----------
#define VPS 40
#define SMS 65
#define DIV7(t) (((t) * 9363) >> 16)
#define LPOF(t) ((t) + 7 * DIV7(t))

__global__ __launch_bounds__(256, 5) void attn_fused_k(
    const u8* __restrict__ qk8, const u8* __restrict__ wTs8,
    const u16* __restrict__ vT,
    const float* __restrict__ dm_b, const float* __restrict__ rel_bias,
    u8* __restrict__ attnoT8) {
  __shared__ __align__(16) u16 shraw[14216];   // 28432 B -> 5 blocks/CU
  u8* patchB = (u8*)shraw;                     // phase1: 196 x 64B = 12.5 KB
  int img = blockIdx.x / 49;
  int tile = blockIdx.x % 49;
  int y0 = (tile / 7) * 8, x0 = (tile % 7) * 8;
  int tid = threadIdx.x;
  const u8* qimg = qk8 + (size_t)img * PIX * 64;
  for (int idx = tid; idx < 784; idx += 256) {
    int lp = idx >> 2, slot = idx & 3;
    int r = lp / 14, c = lp - r * 14;
    int gy = y0 - 3 + r, gx = x0 - 3 + c;
    uint4v val = {0u, 0u, 0u, 0u};
    if ((unsigned)gy < 56u && (unsigned)gx < 56u)
      val = *(const uint4v*)(qimg + (size_t)(gy * 56 + gx) * 64 + slot * 16);
    *(uint4v*)&patchB[lp * 64 + ((slot ^ ((lp >> 1) & 3)) << 4)] = val;
  }
  __syncthreads();

  // T14: issue V-patch global loads now; LDS-write after the MFMA phase.
  const u16* vbase = vT + (size_t)img * PIX * 32;
  uint4v vreg[4];
#pragma unroll
  for (int s = 0; s < 4; s++) {
    int idx = s * 256 + tid;
    uint4v val = {0u, 0u, 0u, 0u};
    if (s < 3 || idx < 784) {
      int g = idx & 3, lp = idx >> 2;
      int r = lp / 14, c = lp - r * 14;
      int gy = y0 - 3 + r, gx = x0 - 3 + c;
      if ((unsigned)gy < 56u && (unsigned)gx < 56u)
        val = *(const uint4v*)(vbase + (size_t)(gy * 56 + gx) * 32 + g * 8);
    }
    vreg[s] = val;
  }

  int lane = tid & 63, wid = tid >> 6;
  int Mtile = wid & 1, Ntile = wid >> 1;
  int n = lane & 31, hi = lane >> 5;
  int py = Ntile * 4 + (n >> 3), px = n & 7;
  int lpb = py * 14 + px;
  f32x16 acc0, acc1;
#pragma unroll
  for (int i = 0; i < 16; i++) { acc0[i] = 0.f; acc1[i] = 0.f; }

  const u8* Aw = wTs8 + Mtile * 2048 + lane * 32;
#pragma unroll
  for (int tap = 0; tap < KWIN; tap++) {
    int lp_ = lpb + LPOF(tap);
    const int4x* ap = (const int4x*)(Aw + tap * 4096);
    int4x alo = ap[0], ahi = ap[1];
    int sw = (lp_ >> 1) & 3;
    int4x blo = *(const int4x*)&patchB[lp_ * 64 + (((2 * hi) ^ sw) << 4)];
    int4x bhi = *(const int4x*)&patchB[lp_ * 64 + (((2 * hi + 1) ^ sw) << 4)];
    int8x a = __builtin_shufflevector(alo, ahi, 0, 1, 2, 3, 4, 5, 6, 7);
    int8x b = __builtin_shufflevector(blo, bhi, 0, 1, 2, 3, 4, 5, 6, 7);
    if (tap & 1)
      acc1 = __builtin_amdgcn_mfma_scale_f32_32x32x64_f8f6f4(
          a, b, acc1, 0, 0, 0, 127, 0, 127);
    else
      acc0 = __builtin_amdgcn_mfma_scale_f32_32x32x64_f8f6f4(
          a, b, acc0, 0, 0, 0, 127, 0, 127);
  }

  // ---- fused tail: logits -> smx[49][SMS], vreg -> vp, softmax, PV ---------
  __syncthreads();
  float* smx = (float*)shraw;            // 49 x 65 x 4 = 12740 B
  u16* vp = shraw + 6376;                // [196 pix][VPS] bf16 (15680 B)
  int head = img % NHEADS;
#pragma unroll
  for (int r = 0; r < 16; r++) {
    int ko = Mtile * 32 + (r & 3) + 8 * (r >> 2) + 4 * hi;
    if (ko < KWIN)
      smx[ko * SMS + Ntile * 32 + n] =
          acc0[r] + acc1[r] + dm_b[ko] + rel_bias[ko * NHEADS + head];
  }
#pragma unroll
  for (int s = 0; s < 4; s++) {
    int idx = s * 256 + tid;
    if (s < 3 || idx < 784) {
      int g = idx & 3, lp = idx >> 2;
      *(uint4v*)&vp[lp * VPS + g * 8] = vreg[s];
    }
  }
  __syncthreads();
  {
    int pxs = tid >> 2, q4 = tid & 3;
    int k0 = q4 * 13;
    int k1 = (q4 == 3) ? KWIN : k0 + 13;
    float m = -1e30f;
    for (int k = k0; k < k1; k++) m = fmaxf(m, smx[k * SMS + pxs]);
    m = fmaxf(m, __shfl_xor(m, 1, 64));
    m = fmaxf(m, __shfl_xor(m, 2, 64));
    float ssum = 0.f;
    for (int k = k0; k < k1; k++) {
      float e = __expf(smx[k * SMS + pxs] - m);
      smx[k * SMS + pxs] = e;
      ssum += e;
    }
    ssum += __shfl_xor(ssum, 1, 64);
    ssum += __shfl_xor(ssum, 2, 64);
    float inv = 1.f / ssum;
    for (int k = k0; k < k1; k++) smx[k * SMS + pxs] *= inv;
  }
  __syncthreads();
  int pxl = tid & 63, co = tid >> 6;
  int pyy = pxl >> 3, pxx = pxl & 7;
  float o8[8] = {0.f, 0.f, 0.f, 0.f, 0.f, 0.f, 0.f, 0.f};
#pragma unroll
  for (int kh = 0; kh < 7; kh++) {
#pragma unroll
    for (int kw = 0; kw < 7; kw++) {
      float p = smx[(kh * 7 + kw) * SMS + pxl];
      bf16x8 v = *(const bf16x8*)&vp[((pyy + kh) * 14 + pxx + kw) * VPS + co * 8];
#pragma unroll
      for (int j = 0; j < 8; j++) o8[j] += p * (float)v[j];
    }
  }
  int gp = (y0 + pyy) * 56 + x0 + pxx;
  int b = img / NHEADS;
  uint2v w = f32x8_to_fp8(o8);
  *(uint2v*)(attnoT8 + ((size_t)b * PIX + gp) * CDIM + head * 32 + co * 8) = w;
}

// ---------------- launch ----------------------------------------------------
extern "C" void kernel_launch(void* const* d_in, const int* in_sizes, int n_in,
                              void* d_out, int out_size, void* d_ws, size_t ws_size,
                              hipStream_t stream) {
  const float* x        = (const float*)d_in[0];
  const float* bn_gamma = (const float*)d_in[1];
  const float* bn_beta  = (const float*)d_in[2];
  const float* qkv_w    = (const float*)d_in[3];
  const float* qkv_b    = (const float*)d_in[4];
  const float* dm_w     = (const float*)d_in[5];
  const float* dm_b     = (const float*)d_in[6];
  const float* rel_bias = (const float*)d_in[7];
  const float* proj_w   = (const float*)d_in[8];
  const float* proj_b   = (const float*)d_in[9];
  const float* c1_w     = (const float*)d_in[10];
  const float* c1_b     = (const float*)d_in[11];
  const float* c2_w     = (const float*)d_in[12];
  const float* c2_b     = (const float*)d_in[13];
  float* out = (float*)d_out;
  float* ws  = (float*)d_ws;

  float* stats    = ws;                            // 384 f
  float* b_eff    = stats + 384;                   // 576 f
  u8*    pk_qkv8  = (u8*)(b_eff + 576);            // 110592 B
  u8*    pk_proj8 = pk_qkv8 + 110592;              // 36864 B
  u8*    pk_c18   = pk_proj8 + 36864;              // 147456 B
  u8*    pk_c28   = pk_c18 + 147456;               // 147456 B
  u8*    wTs8     = pk_c28 + 147456;               // 200704 B
  u8*    xT8      = wTs8 + 200704;                 // 2408448 B
  u8*    qk8      = xT8 + 2408448;                 // 4816896 B
  u16*   vT       = (u16*)(qk8 + 4816896);         // 2408448 u16
  u8*    attnoT8  = (u8*)(vT + 2408448);           // 2408448 B
  float* x1       = (float*)(attnoT8 + 2408448);   // 2408448 f
  u8*    x1T8     = (u8*)(x1 + 2408448);           // 2408448 B
  u8*    hT8      = x1T8 + 2408448;                // 9633792 B

  bn_stats_k<<<CDIM, 256, 0, stream>>>(x, stats);
  prep5_k<<<2577, 256, 0, stream>>>(qkv_w, qkv_b, bn_gamma, bn_beta, stats,
                                    pk_qkv8, b_eff, dm_w, wTs8,
                                    proj_w, pk_proj8, c1_w, pk_c18,
                                    c2_w, pk_c28, x, xT8);

  mgemm8_k<MG_QKV><<<dim3(98, 9), 256, 0, stream>>>(
      xT8, pk_qkv8, b_eff, nullptr, nullptr, vT, qk8, nullptr, 192);
  attn_fused_k<<<NIMG * 49, 256, 0, stream>>>(qk8, wTs8, vT, dm_b, rel_bias, attnoT8);
  mgemm8_k<MG_PROJ><<<dim3(98, 3), 256, 0, stream>>>(
      attnoT8, pk_proj8, proj_b, x1, x1T8, nullptr, nullptr, x, 192);
  mgemm8_k<MG_GELU><<<dim3(98, 12), 256, 0, stream>>>(
      x1T8, pk_c18, c1_b, nullptr, hT8, nullptr, nullptr, nullptr, 192);
  mgemm8_k<MG_C2><<<dim3(98, 3), 256, 0, stream>>>(
      hT8, pk_c28, c2_b, out, nullptr, nullptr, nullptr, x1, 768);
}

// Round 20
// 97.186 us; speedup vs baseline: 1.9735x; 1.0079x over previous
//
#include <hip/hip_runtime.h>
#include <hip/hip_bf16.h>
#include <math.h>

#define CDIM 192
#define NHEADS 6
#define WIN 7
#define KWIN 49
#define BATCH 4
#define PIX 3136      // 56*56
#define NPIX 12544    // BATCH*PIX
#define NIMG 24       // BATCH*NHEADS
#define EPSV 1e-5f

typedef __bf16 bf16x8 __attribute__((ext_vector_type(8)));
typedef float f32x16 __attribute__((ext_vector_type(16)));
typedef unsigned int uint4v __attribute__((ext_vector_type(4)));
typedef unsigned int uint2v __attribute__((ext_vector_type(2)));
typedef int int4x __attribute__((ext_vector_type(4)));
typedef int int8x __attribute__((ext_vector_type(8)));
typedef unsigned short u16;
typedef unsigned char u8;

__device__ inline u8 f32_to_fp8(float v) {
  return (u8)(__builtin_amdgcn_cvt_pk_fp8_f32(v, 0.f, 0, false) & 0xFF);
}

// 8 bf16 (as uint4v) -> 8 fp8 bytes
__device__ inline uint2v bf8_to_fp8x8(uint4v v) {
  const u16* h = (const u16*)&v;
  float f[8];
#pragma unroll
  for (int e = 0; e < 8; e++) {
    unsigned u = ((unsigned)h[e]) << 16;
    f[e] = __builtin_bit_cast(float, u);
  }
  int lo = __builtin_amdgcn_cvt_pk_fp8_f32(f[0], f[1], 0, false);
  lo = __builtin_amdgcn_cvt_pk_fp8_f32(f[2], f[3], lo, true);
  int hi = __builtin_amdgcn_cvt_pk_fp8_f32(f[4], f[5], 0, false);
  hi = __builtin_amdgcn_cvt_pk_fp8_f32(f[6], f[7], hi, true);
  uint2v r = {(unsigned)lo, (unsigned)hi};
  return r;
}

// 8 f32 -> 8 fp8 bytes
__device__ inline uint2v f32x8_to_fp8(const float* f) {
  int lo = __builtin_amdgcn_cvt_pk_fp8_f32(f[0], f[1], 0, false);
  lo = __builtin_amdgcn_cvt_pk_fp8_f32(f[2], f[3], lo, true);
  int hi = __builtin_amdgcn_cvt_pk_fp8_f32(f[4], f[5], 0, false);
  hi = __builtin_amdgcn_cvt_pk_fp8_f32(f[6], f[7], hi, true);
  uint2v r = {(unsigned)lo, (unsigned)hi};
  return r;
}

// ---------------- BN stats ---------------------------------------------------
__global__ __launch_bounds__(256) void bn_stats_k(const float* __restrict__ x,
                                                  float* __restrict__ stats) {
  int c = blockIdx.x;
  float s = 0.f, q = 0.f;
  for (int n = threadIdx.x; n < BATCH * PIX; n += 256) {
    int b = n / PIX, p = n - b * PIX;
    float v = x[((size_t)b * CDIM + c) * PIX + p];
    s += v; q += v * v;
  }
  __shared__ float rs[256], rq[256];
  rs[threadIdx.x] = s; rq[threadIdx.x] = q;
  __syncthreads();
  for (int st = 128; st > 0; st >>= 1) {
    if (threadIdx.x < st) { rs[threadIdx.x] += rs[threadIdx.x + st]; rq[threadIdx.x] += rq[threadIdx.x + st]; }
    __syncthreads();
  }
  if (threadIdx.x == 0) {
    float mean = rs[0] / (float)(BATCH * PIX);
    float var = rq[0] / (float)(BATCH * PIX) - mean * mean;
    stats[c] = mean;
    stats[CDIM + c] = rsqrtf(var + EPSV);
  }
}

// -------- fp8 K=64 frag pack: W[Cout][Cin] -> [oT][kc][lane][32B] -----------
__device__ inline void pack8_one(const float* __restrict__ W, u8* __restrict__ out,
                                 int Cin, int t, int total) {
  if (t >= total) return;
  int lane = t & 63, rest = t >> 6;
  int nKC = Cin >> 6;
  int kc = rest % nKC, oT = rest / nKC;
  int o = oT * 32 + (lane & 31), c = kc * 64 + (lane >> 5) * 32;
  const float* src = W + (size_t)o * Cin + c;
  u8 tmp[32];
#pragma unroll
  for (int e = 0; e < 32; e++) tmp[e] = f32_to_fp8(src[e]);
  *(uint4v*)(out + (size_t)t * 32) = *(uint4v*)tmp;
  *(uint4v*)(out + (size_t)t * 32 + 16) = *(uint4v*)(tmp + 16);
}

// --- merged prep: qkv fold->fp8 frags, dm_w fp8, proj/c1/c2 fp8, xT8 --------
__global__ __launch_bounds__(256) void prep5_k(
    const float* __restrict__ qkv_w, const float* __restrict__ qkv_b,
    const float* __restrict__ gamma, const float* __restrict__ beta,
    const float* __restrict__ stats, u8* __restrict__ pk_qkv8,
    float* __restrict__ b_eff,
    const float* __restrict__ dm_w, u8* __restrict__ wTs8,
    const float* __restrict__ proj_w, u8* __restrict__ pk_proj8,
    const float* __restrict__ c1_w, u8* __restrict__ pk_c18,
    const float* __restrict__ c2_w, u8* __restrict__ pk_c28,
    const float* __restrict__ x, u8* __restrict__ xT8) {
  __shared__ float shf[64 * 33];
  int bid = blockIdx.x, tid = threadIdx.x;
  if (bid < 576) {
    int o = bid;
    float* r = shf;
    if (tid < CDIM) {
      int c = tid;
      float alpha = gamma[c] * stats[CDIM + c];
      float shift = beta[c] - stats[c] * alpha;
      float w = qkv_w[o * CDIM + c];
      float scale = (o < CDIM) ? 0.17677669529663687f : 1.f;
      int bidx = (((o >> 5) * 3 + (c >> 6)) * 64 + (((c >> 5) & 1) * 32 + (o & 31))) * 32 + (c & 31);
      pk_qkv8[bidx] = f32_to_fp8(w * alpha * scale);
      r[c] = w * shift;
    }
    __syncthreads();
    if (tid == 0) {
      float s = 0.f;
      for (int i = 0; i < CDIM; i++) s += r[i];
      float scale = (o < CDIM) ? 0.17677669529663687f : 1.f;
      b_eff[o] = (qkv_b[o] + s) * scale;
    }
  } else if (bid < 1360) {
    int idx = (bid - 576) * 256 + tid;   // < 200704
    int e = idx & 31;
    int tmp = idx >> 5;
    int lane = tmp & 63; tmp >>= 6;
    int Mt = tmp & 1;
    int tap = tmp >> 1;                  // 0..48
    int ko = Mt * 32 + (lane & 31);
    int ci = (lane >> 5) * 32 + e;
    float v = (ko < KWIN) ? dm_w[(size_t)ko * 3136 + ci * 49 + tap] : 0.f;
    wTs8[idx] = f32_to_fp8(v);
  } else if (bid < 1365) {
    pack8_one(proj_w, pk_proj8, 192, (bid - 1360) * 256 + tid, 1152);
  } else if (bid < 1383) {
    pack8_one(c1_w, pk_c18, 192, (bid - 1365) * 256 + tid, 4608);
  } else if (bid < 1401) {
    pack8_one(c2_w, pk_c28, 768, (bid - 1383) * 256 + tid, 4608);
  } else {
    int t = bid - 1401;                 // [0,1176): x -> xT8 transpose + fp8
    int bx = t % 196, by = t / 196;
    int bb = bx / 49;
    int p0 = (bx % 49) * 64;
    int c0 = by * 32;
    float (*Ls)[33] = (float(*)[33])shf;
    int j = tid & 63;
#pragma unroll
    for (int it = 0; it < 8; it++) {
      int c = it * 4 + (tid >> 6);
      Ls[j][c] = x[((size_t)bb * CDIM + c0 + c) * PIX + p0 + j];
    }
    __syncthreads();
    int jr = tid >> 2, tt = tid & 3;
    float f[8];
#pragma unroll
    for (int u = 0; u < 8; u++) f[u] = Ls[jr][tt * 8 + u];
    uint2v w = f32x8_to_fp8(f);
    *(uint2v*)(xT8 + (size_t)(bb * PIX + p0 + jr) * CDIM + c0 + tt * 8) = w;
  }
}

// ----- MX-fp8 MFMA GEMM: 128px x 64o, K=64 chunks, dbuf async staging -------
#define MG_QKV 0
#define MG_PROJ 1
#define MG_GELU 2
#define MG_C2 3

template <int EPI>
__global__ __launch_bounds__(256, 5) void mgemm8_k(
    const u8* __restrict__ Bm8, const u8* __restrict__ Apk8,
    const float* __restrict__ bias,
    float* __restrict__ outF, u8* __restrict__ outT8, u16* __restrict__ outT2,
    u8* __restrict__ outQK8,
    const float* __restrict__ extra, int Cin) {
  __shared__ __align__(16) u8 Bs8[2][8192];   // [px 128][64B]
  __shared__ __align__(16) u8 As8[2][4096];   // [mt 2][lane 64][32B]
  int tid = threadIdx.x;
  int lane = tid & 63, wid = tid >> 6;
  int hi = lane >> 5, ln31 = lane & 31;
  int p0 = blockIdx.x * 128;
  int o0 = blockIdx.y * 64;
  int nKC = Cin >> 6;
  f32x16 acc[2];
#pragma unroll
  for (int mt = 0; mt < 2; mt++)
#pragma unroll
    for (int i = 0; i < 16; i++) acc[mt][i] = 0.f;

  uint4v bReg[2], aReg;
  auto loadC = [&](int kc) {
    int cc = kc * 64;
#pragma unroll
    for (int i = 0; i < 2; i++) {
      int idx = i * 256 + tid;
      int px = idx >> 2, slot = idx & 3;
      bReg[i] = *(const uint4v*)(Bm8 + (size_t)(p0 + px) * Cin + cc + slot * 16);
    }
    int frag = tid >> 7, off = (tid & 127) * 16;
    aReg = *(const uint4v*)(Apk8 + (size_t)(((o0 >> 5) + frag) * nKC + kc) * 2048 + off);
  };
  auto storeC = [&](int buf) {
#pragma unroll
    for (int i = 0; i < 2; i++) {
      int idx = i * 256 + tid;
      int px = idx >> 2, slot = idx & 3;
      *(uint4v*)&Bs8[buf][px * 64 + ((slot ^ (px & 3)) << 4)] = bReg[i];
    }
    int frag = tid >> 7, off = (tid & 127) * 16;
    *(uint4v*)&As8[buf][frag * 2048 + off] = aReg;
  };

  loadC(0);
  storeC(0);
  __syncthreads();
  int pxw = wid * 32 + ln31;
  int swb = pxw & 3;
  for (int kc = 0; kc < nKC; kc++) {
    int cur = kc & 1;
    bool more = (kc + 1 < nKC);
    if (more) loadC(kc + 1);            // global loads overlap MFMAs
    int4x a0lo = *(const int4x*)&As8[cur][lane * 32];
    int4x a0hi = *(const int4x*)&As8[cur][lane * 32 + 16];
    int4x a1lo = *(const int4x*)&As8[cur][2048 + lane * 32];
    int4x a1hi = *(const int4x*)&As8[cur][2048 + lane * 32 + 16];
    int4x blo = *(const int4x*)&Bs8[cur][pxw * 64 + (((2 * hi) ^ swb) << 4)];
    int4x bhi = *(const int4x*)&Bs8[cur][pxw * 64 + (((2 * hi + 1) ^ swb) << 4)];
    int8x a0 = __builtin_shufflevector(a0lo, a0hi, 0, 1, 2, 3, 4, 5, 6, 7);
    int8x a1 = __builtin_shufflevector(a1lo, a1hi, 0, 1, 2, 3, 4, 5, 6, 7);
    int8x b = __builtin_shufflevector(blo, bhi, 0, 1, 2, 3, 4, 5, 6, 7);
    acc[0] = __builtin_amdgcn_mfma_scale_f32_32x32x64_f8f6f4(
        a0, b, acc[0], 0, 0, 0, 127, 0, 127);
    acc[1] = __builtin_amdgcn_mfma_scale_f32_32x32x64_f8f6f4(
        a1, b, acc[1], 0, 0, 0, 127, 0, 127);
    if (more) storeC(cur ^ 1);
    __syncthreads();
  }

  // ---- epilogue ----
  if (EPI == MG_C2) {
#pragma unroll
    for (int mt = 0; mt < 2; mt++)
#pragma unroll
      for (int r = 0; r < 16; r++) {
        int o = o0 + mt * 32 + (r & 3) + 8 * (r >> 2) + 4 * hi;
        float bv = bias[o];
        unsigned gp = p0 + pxw;
        unsigned bb = gp / PIX, pp = gp - bb * PIX;
        size_t oi = ((size_t)bb * CDIM + o) * PIX + pp;
        outF[oi] = acc[mt][r] + bv + extra[oi];
      }
  } else {
    u16* scratch = (u16*)Bs8;           // 128 rows x 64 o x 2B = 16 KB
#pragma unroll
    for (int mt = 0; mt < 2; mt++)
#pragma unroll
      for (int r = 0; r < 16; r++) {
        int o_loc = mt * 32 + (r & 3) + 8 * (r >> 2) + 4 * hi;
        int o = o0 + o_loc;
        float bv = bias[o];
        int p_loc = pxw;
        float val = acc[mt][r] + bv;
        if (EPI == MG_PROJ) {
          unsigned gp = p0 + p_loc;
          unsigned bb = gp / PIX, pp = gp - bb * PIX;
          size_t oi = ((size_t)bb * CDIM + o) * PIX + pp;
          val += extra[oi];
          outF[oi] = val;               // x1 fp32 (residual included)
        }
        if (EPI == MG_GELU)
          val = 0.5f * val * (1.f + erff(val * 0.70710678118654752f));
        *(__hip_bfloat16*)&scratch[p_loc * 64 + (((o_loc >> 3) ^ (p_loc & 7)) << 3) + (o_loc & 7)] =
            __float2bfloat16(val);
      }
    __syncthreads();
    int prow = tid >> 1, half = tid & 1;
    int psw = prow & 7;
    uint4v r4[4];
#pragma unroll
    for (int j = 0; j < 4; j++)
      r4[j] = *(const uint4v*)&scratch[prow * 64 + ((((half << 2) + j) ^ psw) << 3)];
    unsigned gp = p0 + prow;
    if (EPI == MG_QKV) {
      unsigned bb = gp / PIX, pp = gp - bb * PIX;
      int s = o0 / 192;               // 0=q, 1=k, 2=v
      int h0 = ((o0 - s * 192) >> 5) + half;
      if (s < 2) {
        uint2v c0 = bf8_to_fp8x8(r4[0]), c1 = bf8_to_fp8x8(r4[1]);
        uint2v c2 = bf8_to_fp8x8(r4[2]), c3 = bf8_to_fp8x8(r4[3]);
        uint4v w0 = {c0[0], c0[1], c1[0], c1[1]};
        uint4v w1 = {c2[0], c2[1], c3[0], c3[1]};
        u8* d = outQK8 + ((size_t)(bb * NHEADS + h0) * PIX + pp) * 64 + s * 32;
        *(uint4v*)(d) = w0; *(uint4v*)(d + 16) = w1;
      } else {                        // v -> vT[img][pix][32] bf16
        u16* d = outT2 + ((size_t)(bb * NHEADS + h0) * PIX + pp) * 32;
        *(uint4v*)(d) = r4[0]; *(uint4v*)(d + 8) = r4[1];
        *(uint4v*)(d + 16) = r4[2]; *(uint4v*)(d + 24) = r4[3];
      }
    } else {  // PROJ -> x1T8 [gp][192] fp8; GELU -> hT8 [gp][768] fp8
      uint2v c0 = bf8_to_fp8x8(r4[0]), c1 = bf8_to_fp8x8(r4[1]);
      uint2v c2 = bf8_to_fp8x8(r4[2]), c3 = bf8_to_fp8x8(r4[3]);
      uint4v w0 = {c0[0], c0[1], c1[0], c1[1]};
      uint4v w1 = {c2[0], c2[1], c3[0], c3[1]};
      int stride = (EPI == MG_PROJ) ? CDIM : 768;
      u8* d = outT8 + (size_t)gp * stride + o0 + half * 32;
      *(uint4v*)(d) = w0; *(uint4v*)(d + 16) = w1;
    }
  }
}

// ------ 7x7 attn conv (MX fp8 K=64) + fused softmax/PV, XCD-swizzled --------
#define VPS 40
#define SMS 65
#define DIV7(t) (((t) * 9363) >> 16)
#define LPOF(t) ((t) + 7 * DIV7(t))

__global__ __launch_bounds__(256, 5) void attn_fused_k(
    const u8* __restrict__ qk8, const u8* __restrict__ wTs8,
    const u16* __restrict__ vT,
    const float* __restrict__ dm_b, const float* __restrict__ rel_bias,
    u8* __restrict__ attnoT8) {
  __shared__ __align__(16) u16 shraw[14216];   // 28432 B -> 5 blocks/CU
  u8* patchB = (u8*)shraw;                     // phase1: 196 x 64B = 12.5 KB
  // T1 XCD swizzle: grid 1176 = 8 x 147; each XCD gets 147 contiguous logical
  // blocks = exactly 3 images -> qk8/vT reads become XCD-L2-local.
  int bid = (blockIdx.x & 7) * 147 + (blockIdx.x >> 3);
  int img = bid / 49;
  int tile = bid % 49;
  int y0 = (tile / 7) * 8, x0 = (tile % 7) * 8;
  int tid = threadIdx.x;
  const u8* qimg = qk8 + (size_t)img * PIX * 64;
  for (int idx = tid; idx < 784; idx += 256) {
    int lp = idx >> 2, slot = idx & 3;
    int r = lp / 14, c = lp - r * 14;
    int gy = y0 - 3 + r, gx = x0 - 3 + c;
    uint4v val = {0u, 0u, 0u, 0u};
    if ((unsigned)gy < 56u && (unsigned)gx < 56u)
      val = *(const uint4v*)(qimg + (size_t)(gy * 56 + gx) * 64 + slot * 16);
    *(uint4v*)&patchB[lp * 64 + ((slot ^ ((lp >> 1) & 3)) << 4)] = val;
  }
  __syncthreads();

  // T14: issue V-patch global loads now; LDS-write after the MFMA phase.
  const u16* vbase = vT + (size_t)img * PIX * 32;
  uint4v vreg[4];
#pragma unroll
  for (int s = 0; s < 4; s++) {
    int idx = s * 256 + tid;
    uint4v val = {0u, 0u, 0u, 0u};
    if (s < 3 || idx < 784) {
      int g = idx & 3, lp = idx >> 2;
      int r = lp / 14, c = lp - r * 14;
      int gy = y0 - 3 + r, gx = x0 - 3 + c;
      if ((unsigned)gy < 56u && (unsigned)gx < 56u)
        val = *(const uint4v*)(vbase + (size_t)(gy * 56 + gx) * 32 + g * 8);
    }
    vreg[s] = val;
  }

  int lane = tid & 63, wid = tid >> 6;
  int Mtile = wid & 1, Ntile = wid >> 1;
  int n = lane & 31, hi = lane >> 5;
  int py = Ntile * 4 + (n >> 3), px = n & 7;
  int lpb = py * 14 + px;
  f32x16 acc0, acc1;
#pragma unroll
  for (int i = 0; i < 16; i++) { acc0[i] = 0.f; acc1[i] = 0.f; }

  const u8* Aw = wTs8 + Mtile * 2048 + lane * 32;
#pragma unroll
  for (int tap = 0; tap < KWIN; tap++) {
    int lp_ = lpb + LPOF(tap);
    const int4x* ap = (const int4x*)(Aw + tap * 4096);
    int4x alo = ap[0], ahi = ap[1];
    int sw = (lp_ >> 1) & 3;
    int4x blo = *(const int4x*)&patchB[lp_ * 64 + (((2 * hi) ^ sw) << 4)];
    int4x bhi = *(const int4x*)&patchB[lp_ * 64 + (((2 * hi + 1) ^ sw) << 4)];
    int8x a = __builtin_shufflevector(alo, ahi, 0, 1, 2, 3, 4, 5, 6, 7);
    int8x b = __builtin_shufflevector(blo, bhi, 0, 1, 2, 3, 4, 5, 6, 7);
    if (tap & 1)
      acc1 = __builtin_amdgcn_mfma_scale_f32_32x32x64_f8f6f4(
          a, b, acc1, 0, 0, 0, 127, 0, 127);
    else
      acc0 = __builtin_amdgcn_mfma_scale_f32_32x32x64_f8f6f4(
          a, b, acc0, 0, 0, 0, 127, 0, 127);
  }

  // ---- fused tail: logits -> smx[49][SMS], vreg -> vp, softmax, PV ---------
  __syncthreads();
  float* smx = (float*)shraw;            // 49 x 65 x 4 = 12740 B
  u16* vp = shraw + 6376;                // [196 pix][VPS] bf16 (15680 B)
  int head = img % NHEADS;
#pragma unroll
  for (int r = 0; r < 16; r++) {
    int ko = Mtile * 32 + (r & 3) + 8 * (r >> 2) + 4 * hi;
    if (ko < KWIN)
      smx[ko * SMS + Ntile * 32 + n] =
          acc0[r] + acc1[r] + dm_b[ko] + rel_bias[ko * NHEADS + head];
  }
#pragma unroll
  for (int s = 0; s < 4; s++) {
    int idx = s * 256 + tid;
    if (s < 3 || idx < 784) {
      int g = idx & 3, lp = idx >> 2;
      *(uint4v*)&vp[lp * VPS + g * 8] = vreg[s];
    }
  }
  __syncthreads();
  {
    int pxs = tid >> 2, q4 = tid & 3;
    int k0 = q4 * 13;
    int k1 = (q4 == 3) ? KWIN : k0 + 13;
    float m = -1e30f;
    for (int k = k0; k < k1; k++) m = fmaxf(m, smx[k * SMS + pxs]);
    m = fmaxf(m, __shfl_xor(m, 1, 64));
    m = fmaxf(m, __shfl_xor(m, 2, 64));
    float ssum = 0.f;
    for (int k = k0; k < k1; k++) {
      float e = __expf(smx[k * SMS + pxs] - m);
      smx[k * SMS + pxs] = e;
      ssum += e;
    }
    ssum += __shfl_xor(ssum, 1, 64);
    ssum += __shfl_xor(ssum, 2, 64);
    float inv = 1.f / ssum;
    for (int k = k0; k < k1; k++) smx[k * SMS + pxs] *= inv;
  }
  __syncthreads();
  int pxl = tid & 63, co = tid >> 6;
  int pyy = pxl >> 3, pxx = pxl & 7;
  float o8[8] = {0.f, 0.f, 0.f, 0.f, 0.f, 0.f, 0.f, 0.f};
#pragma unroll
  for (int kh = 0; kh < 7; kh++) {
#pragma unroll
    for (int kw = 0; kw < 7; kw++) {
      float p = smx[(kh * 7 + kw) * SMS + pxl];
      bf16x8 v = *(const bf16x8*)&vp[((pyy + kh) * 14 + pxx + kw) * VPS + co * 8];
#pragma unroll
      for (int j = 0; j < 8; j++) o8[j] += p * (float)v[j];
    }
  }
  int gp = (y0 + pyy) * 56 + x0 + pxx;
  int b = img / NHEADS;
  uint2v w = f32x8_to_fp8(o8);
  *(uint2v*)(attnoT8 + ((size_t)b * PIX + gp) * CDIM + head * 32 + co * 8) = w;
}

// ---------------- launch ----------------------------------------------------
extern "C" void kernel_launch(void* const* d_in, const int* in_sizes, int n_in,
                              void* d_out, int out_size, void* d_ws, size_t ws_size,
                              hipStream_t stream) {
  const float* x        = (const float*)d_in[0];
  const float* bn_gamma = (const float*)d_in[1];
  const float* bn_beta  = (const float*)d_in[2];
  const float* qkv_w    = (const float*)d_in[3];
  const float* qkv_b    = (const float*)d_in[4];
  const float* dm_w     = (const float*)d_in[5];
  const float* dm_b     = (const float*)d_in[6];
  const float* rel_bias = (const float*)d_in[7];
  const float* proj_w   = (const float*)d_in[8];
  const float* proj_b   = (const float*)d_in[9];
  const float* c1_w     = (const float*)d_in[10];
  const float* c1_b     = (const float*)d_in[11];
  const float* c2_w     = (const float*)d_in[12];
  const float* c2_b     = (const float*)d_in[13];
  float* out = (float*)d_out;
  float* ws  = (float*)d_ws;

  float* stats    = ws;                            // 384 f
  float* b_eff    = stats + 384;                   // 576 f
  u8*    pk_qkv8  = (u8*)(b_eff + 576);            // 110592 B
  u8*    pk_proj8 = pk_qkv8 + 110592;              // 36864 B
  u8*    pk_c18   = pk_proj8 + 36864;              // 147456 B
  u8*    pk_c28   = pk_c18 + 147456;               // 147456 B
  u8*    wTs8     = pk_c28 + 147456;               // 200704 B
  u8*    xT8      = wTs8 + 200704;                 // 2408448 B
  u8*    qk8      = xT8 + 2408448;                 // 4816896 B
  u16*   vT       = (u16*)(qk8 + 4816896);         // 2408448 u16
  u8*    attnoT8  = (u8*)(vT + 2408448);           // 2408448 B
  float* x1       = (float*)(attnoT8 + 2408448);   // 2408448 f
  u8*    x1T8     = (u8*)(x1 + 2408448);           // 2408448 B
  u8*    hT8      = x1T8 + 2408448;                // 9633792 B

  bn_stats_k<<<CDIM, 256, 0, stream>>>(x, stats);
  prep5_k<<<2577, 256, 0, stream>>>(qkv_w, qkv_b, bn_gamma, bn_beta, stats,
                                    pk_qkv8, b_eff, dm_w, wTs8,
                                    proj_w, pk_proj8, c1_w, pk_c18,
                                    c2_w, pk_c28, x, xT8);

  mgemm8_k<MG_QKV><<<dim3(98, 9), 256, 0, stream>>>(
      xT8, pk_qkv8, b_eff, nullptr, nullptr, vT, qk8, nullptr, 192);
  attn_fused_k<<<NIMG * 49, 256, 0, stream>>>(qk8, wTs8, vT, dm_b, rel_bias, attnoT8);
  mgemm8_k<MG_PROJ><<<dim3(98, 3), 256, 0, stream>>>(
      attnoT8, pk_proj8, proj_b, x1, x1T8, nullptr, nullptr, x, 192);
  mgemm8_k<MG_GELU><<<dim3(98, 12), 256, 0, stream>>>(
      x1T8, pk_c18, c1_b, nullptr, hT8, nullptr, nullptr, nullptr, 192);
  mgemm8_k<MG_C2><<<dim3(98, 3), 256, 0, stream>>>(
      hT8, pk_c28, c2_b, out, nullptr, nullptr, nullptr, x1, 768);
}

// Round 21
// 95.989 us; speedup vs baseline: 1.9981x; 1.0125x over previous
//
#include <hip/hip_runtime.h>
#include <hip/hip_bf16.h>
#include <math.h>

#define CDIM 192
#define NHEADS 6
#define WIN 7
#define KWIN 49
#define BATCH 4
#define PIX 3136      // 56*56
#define NPIX 12544    // BATCH*PIX
#define NIMG 24       // BATCH*NHEADS
#define EPSV 1e-5f

typedef __bf16 bf16x8 __attribute__((ext_vector_type(8)));
typedef float f32x16 __attribute__((ext_vector_type(16)));
typedef unsigned int uint4v __attribute__((ext_vector_type(4)));
typedef unsigned int uint2v __attribute__((ext_vector_type(2)));
typedef int int4x __attribute__((ext_vector_type(4)));
typedef int int8x __attribute__((ext_vector_type(8)));
typedef unsigned short u16;
typedef unsigned char u8;

__device__ inline u8 f32_to_fp8(float v) {
  return (u8)(__builtin_amdgcn_cvt_pk_fp8_f32(v, 0.f, 0, false) & 0xFF);
}

__device__ inline float bf16_to_f32(u16 h) {
  unsigned u = ((unsigned)h) << 16;
  return __builtin_bit_cast(float, u);
}

// 8 bf16 (as uint4v) -> 8 fp8 bytes
__device__ inline uint2v bf8_to_fp8x8(uint4v v) {
  const u16* h = (const u16*)&v;
  float f[8];
#pragma unroll
  for (int e = 0; e < 8; e++) f[e] = bf16_to_f32(h[e]);
  int lo = __builtin_amdgcn_cvt_pk_fp8_f32(f[0], f[1], 0, false);
  lo = __builtin_amdgcn_cvt_pk_fp8_f32(f[2], f[3], lo, true);
  int hi = __builtin_amdgcn_cvt_pk_fp8_f32(f[4], f[5], 0, false);
  hi = __builtin_amdgcn_cvt_pk_fp8_f32(f[6], f[7], hi, true);
  uint2v r = {(unsigned)lo, (unsigned)hi};
  return r;
}

// 8 f32 -> 8 fp8 bytes
__device__ inline uint2v f32x8_to_fp8(const float* f) {
  int lo = __builtin_amdgcn_cvt_pk_fp8_f32(f[0], f[1], 0, false);
  lo = __builtin_amdgcn_cvt_pk_fp8_f32(f[2], f[3], lo, true);
  int hi = __builtin_amdgcn_cvt_pk_fp8_f32(f[4], f[5], 0, false);
  hi = __builtin_amdgcn_cvt_pk_fp8_f32(f[6], f[7], hi, true);
  uint2v r = {(unsigned)lo, (unsigned)hi};
  return r;
}

// ---------------- BN stats ---------------------------------------------------
__global__ __launch_bounds__(256) void bn_stats_k(const float* __restrict__ x,
                                                  float* __restrict__ stats) {
  int c = blockIdx.x;
  float s = 0.f, q = 0.f;
  for (int n = threadIdx.x; n < BATCH * PIX; n += 256) {
    int b = n / PIX, p = n - b * PIX;
    float v = x[((size_t)b * CDIM + c) * PIX + p];
    s += v; q += v * v;
  }
  __shared__ float rs[256], rq[256];
  rs[threadIdx.x] = s; rq[threadIdx.x] = q;
  __syncthreads();
  for (int st = 128; st > 0; st >>= 1) {
    if (threadIdx.x < st) { rs[threadIdx.x] += rs[threadIdx.x + st]; rq[threadIdx.x] += rq[threadIdx.x + st]; }
    __syncthreads();
  }
  if (threadIdx.x == 0) {
    float mean = rs[0] / (float)(BATCH * PIX);
    float var = rq[0] / (float)(BATCH * PIX) - mean * mean;
    stats[c] = mean;
    stats[CDIM + c] = rsqrtf(var + EPSV);
  }
}

// -------- fp8 K=64 frag pack: W[Cout][Cin] -> [oT][kc][lane][32B] -----------
__device__ inline void pack8_one(const float* __restrict__ W, u8* __restrict__ out,
                                 int Cin, int t, int total) {
  if (t >= total) return;
  int lane = t & 63, rest = t >> 6;
  int nKC = Cin >> 6;
  int kc = rest % nKC, oT = rest / nKC;
  int o = oT * 32 + (lane & 31), c = kc * 64 + (lane >> 5) * 32;
  const float* src = W + (size_t)o * Cin + c;
  u8 tmp[32];
#pragma unroll
  for (int e = 0; e < 32; e++) tmp[e] = f32_to_fp8(src[e]);
  *(uint4v*)(out + (size_t)t * 32) = *(uint4v*)tmp;
  *(uint4v*)(out + (size_t)t * 32 + 16) = *(uint4v*)(tmp + 16);
}

// --- merged prep: qkv fold->fp8 frags, dm_w fp8 (coalesced reads),
//     proj/c1/c2 fp8 packs, x -> xT8 transpose+fp8 ---------------------------
__global__ __launch_bounds__(256) void prep5_k(
    const float* __restrict__ qkv_w, const float* __restrict__ qkv_b,
    const float* __restrict__ gamma, const float* __restrict__ beta,
    const float* __restrict__ stats, u8* __restrict__ pk_qkv8,
    float* __restrict__ b_eff,
    const float* __restrict__ dm_w, u8* __restrict__ wTs8,
    const float* __restrict__ proj_w, u8* __restrict__ pk_proj8,
    const float* __restrict__ c1_w, u8* __restrict__ pk_c18,
    const float* __restrict__ c2_w, u8* __restrict__ pk_c28,
    const float* __restrict__ x, u8* __restrict__ xT8) {
  __shared__ float shf[64 * 33];
  int bid = blockIdx.x, tid = threadIdx.x;
  if (bid < 576) {
    int o = bid;
    float* r = shf;
    if (tid < CDIM) {
      int c = tid;
      float alpha = gamma[c] * stats[CDIM + c];
      float shift = beta[c] - stats[c] * alpha;
      float w = qkv_w[o * CDIM + c];
      float scale = (o < CDIM) ? 0.17677669529663687f : 1.f;
      int bidx = (((o >> 5) * 3 + (c >> 6)) * 64 + (((c >> 5) & 1) * 32 + (o & 31))) * 32 + (c & 31);
      pk_qkv8[bidx] = f32_to_fp8(w * alpha * scale);
      r[c] = w * shift;
    }
    __syncthreads();
    if (tid == 0) {
      float s = 0.f;
      for (int i = 0; i < CDIM; i++) s += r[i];
      float scale = (o < CDIM) ? 0.17677669529663687f : 1.f;
      b_eff[o] = (qkv_b[o] + s) * scale;
    }
  } else if (bid < 1177) {
    // dm_w pack, COALESCED reads: thread t reads dm_w[t] (ko,ci,tap derived).
    // Frag rows ko in [49,64) are never written; their MFMA output rows are
    // discarded by the attn epilogue (ko<49 check), so garbage there is safe.
    int t = (bid - 576) * 256 + tid;     // < 153664 = 49*64*49
    if (t < 153664) {
      int ko = t / 3136;
      int r2 = t - ko * 3136;
      int ci = r2 / 49, tap = r2 - ci * 49;
      int oidx = ((tap * 2 + (ko >> 5)) * 64 + (ci >> 5) * 32 + (ko & 31)) * 32 + (ci & 31);
      wTs8[oidx] = f32_to_fp8(dm_w[t]);
    }
  } else if (bid < 1182) {
    pack8_one(proj_w, pk_proj8, 192, (bid - 1177) * 256 + tid, 1152);
  } else if (bid < 1200) {
    pack8_one(c1_w, pk_c18, 192, (bid - 1182) * 256 + tid, 4608);
  } else if (bid < 1218) {
    pack8_one(c2_w, pk_c28, 768, (bid - 1200) * 256 + tid, 4608);
  } else {
    int t = bid - 1218;                 // [0,1176): x -> xT8 transpose + fp8
    int bx = t % 196, by = t / 196;
    int bb = bx / 49;
    int p0 = (bx % 49) * 64;
    int c0 = by * 32;
    float (*Ls)[33] = (float(*)[33])shf;
    int j = tid & 63;
#pragma unroll
    for (int it = 0; it < 8; it++) {
      int c = it * 4 + (tid >> 6);
      Ls[j][c] = x[((size_t)bb * CDIM + c0 + c) * PIX + p0 + j];
    }
    __syncthreads();
    int jr = tid >> 2, tt = tid & 3;
    float f[8];
#pragma unroll
    for (int u = 0; u < 8; u++) f[u] = Ls[jr][tt * 8 + u];
    uint2v w = f32x8_to_fp8(f);
    *(uint2v*)(xT8 + (size_t)(bb * PIX + p0 + jr) * CDIM + c0 + tt * 8) = w;
  }
}

// ----- MX-fp8 MFMA GEMM: 128px x 64o, K=64 chunks, dbuf async staging -------
#define MG_QKV 0
#define MG_PROJ 1
#define MG_GELU 2
#define MG_C2 3

template <int EPI>
__global__ __launch_bounds__(256, 5) void mgemm8_k(
    const u8* __restrict__ Bm8, const u8* __restrict__ Apk8,
    const float* __restrict__ bias,
    float* __restrict__ outF, u8* __restrict__ outT8, u16* __restrict__ outT2,
    u8* __restrict__ outQK8,
    const float* __restrict__ extra, int Cin) {
  __shared__ __align__(16) u8 Bs8[2][8192];   // [px 128][64B]
  __shared__ __align__(16) u8 As8[2][4096];   // [mt 2][lane 64][32B]
  int tid = threadIdx.x;
  int lane = tid & 63, wid = tid >> 6;
  int hi = lane >> 5, ln31 = lane & 31;
  int p0 = blockIdx.x * 128;
  int o0 = blockIdx.y * 64;
  int nKC = Cin >> 6;
  f32x16 acc[2];
#pragma unroll
  for (int mt = 0; mt < 2; mt++)
#pragma unroll
    for (int i = 0; i < 16; i++) acc[mt][i] = 0.f;

  uint4v bReg[2], aReg;
  auto loadC = [&](int kc) {
    int cc = kc * 64;
#pragma unroll
    for (int i = 0; i < 2; i++) {
      int idx = i * 256 + tid;
      int px = idx >> 2, slot = idx & 3;
      bReg[i] = *(const uint4v*)(Bm8 + (size_t)(p0 + px) * Cin + cc + slot * 16);
    }
    int frag = tid >> 7, off = (tid & 127) * 16;
    aReg = *(const uint4v*)(Apk8 + (size_t)(((o0 >> 5) + frag) * nKC + kc) * 2048 + off);
  };
  auto storeC = [&](int buf) {
#pragma unroll
    for (int i = 0; i < 2; i++) {
      int idx = i * 256 + tid;
      int px = idx >> 2, slot = idx & 3;
      *(uint4v*)&Bs8[buf][px * 64 + ((slot ^ (px & 3)) << 4)] = bReg[i];
    }
    int frag = tid >> 7, off = (tid & 127) * 16;
    *(uint4v*)&As8[buf][frag * 2048 + off] = aReg;
  };

  loadC(0);
  storeC(0);
  __syncthreads();
  int pxw = wid * 32 + ln31;
  int swb = pxw & 3;
  for (int kc = 0; kc < nKC; kc++) {
    int cur = kc & 1;
    bool more = (kc + 1 < nKC);
    if (more) loadC(kc + 1);            // global loads overlap MFMAs
    int4x a0lo = *(const int4x*)&As8[cur][lane * 32];
    int4x a0hi = *(const int4x*)&As8[cur][lane * 32 + 16];
    int4x a1lo = *(const int4x*)&As8[cur][2048 + lane * 32];
    int4x a1hi = *(const int4x*)&As8[cur][2048 + lane * 32 + 16];
    int4x blo = *(const int4x*)&Bs8[cur][pxw * 64 + (((2 * hi) ^ swb) << 4)];
    int4x bhi = *(const int4x*)&Bs8[cur][pxw * 64 + (((2 * hi + 1) ^ swb) << 4)];
    int8x a0 = __builtin_shufflevector(a0lo, a0hi, 0, 1, 2, 3, 4, 5, 6, 7);
    int8x a1 = __builtin_shufflevector(a1lo, a1hi, 0, 1, 2, 3, 4, 5, 6, 7);
    int8x b = __builtin_shufflevector(blo, bhi, 0, 1, 2, 3, 4, 5, 6, 7);
    acc[0] = __builtin_amdgcn_mfma_scale_f32_32x32x64_f8f6f4(
        a0, b, acc[0], 0, 0, 0, 127, 0, 127);
    acc[1] = __builtin_amdgcn_mfma_scale_f32_32x32x64_f8f6f4(
        a1, b, acc[1], 0, 0, 0, 127, 0, 127);
    if (more) storeC(cur ^ 1);
    __syncthreads();
  }

  // ---- epilogue ----
  if (EPI == MG_C2) {
#pragma unroll
    for (int mt = 0; mt < 2; mt++)
#pragma unroll
      for (int r = 0; r < 16; r++) {
        int o = o0 + mt * 32 + (r & 3) + 8 * (r >> 2) + 4 * hi;
        float bv = bias[o];
        unsigned gp = p0 + pxw;
        unsigned bb = gp / PIX, pp = gp - bb * PIX;
        size_t oi = ((size_t)bb * CDIM + o) * PIX + pp;
        outF[oi] = acc[mt][r] + bv + bf16_to_f32(outT2[oi]);  // x1 in bf16
      }
  } else {
    u16* scratch = (u16*)Bs8;           // 128 rows x 64 o x 2B = 16 KB
#pragma unroll
    for (int mt = 0; mt < 2; mt++)
#pragma unroll
      for (int r = 0; r < 16; r++) {
        int o_loc = mt * 32 + (r & 3) + 8 * (r >> 2) + 4 * hi;
        int o = o0 + o_loc;
        float bv = bias[o];
        int p_loc = pxw;
        float val = acc[mt][r] + bv;
        if (EPI == MG_PROJ) {
          unsigned gp = p0 + p_loc;
          unsigned bb = gp / PIX, pp = gp - bb * PIX;
          size_t oi = ((size_t)bb * CDIM + o) * PIX + pp;
          val += extra[oi];
          outT2[oi] = (u16)__bfloat16_as_ushort(__float2bfloat16(val));  // x1 bf16
        }
        if (EPI == MG_GELU)
          val = 0.5f * val * (1.f + erff(val * 0.70710678118654752f));
        *(__hip_bfloat16*)&scratch[p_loc * 64 + (((o_loc >> 3) ^ (p_loc & 7)) << 3) + (o_loc & 7)] =
            __float2bfloat16(val);
      }
    __syncthreads();
    int prow = tid >> 1, half = tid & 1;
    int psw = prow & 7;
    uint4v r4[4];
#pragma unroll
    for (int j = 0; j < 4; j++)
      r4[j] = *(const uint4v*)&scratch[prow * 64 + ((((half << 2) + j) ^ psw) << 3)];
    unsigned gp = p0 + prow;
    if (EPI == MG_QKV) {
      unsigned bb = gp / PIX, pp = gp - bb * PIX;
      int s = o0 / 192;               // 0=q, 1=k, 2=v
      int h0 = ((o0 - s * 192) >> 5) + half;
      if (s < 2) {
        uint2v c0 = bf8_to_fp8x8(r4[0]), c1 = bf8_to_fp8x8(r4[1]);
        uint2v c2 = bf8_to_fp8x8(r4[2]), c3 = bf8_to_fp8x8(r4[3]);
        uint4v w0 = {c0[0], c0[1], c1[0], c1[1]};
        uint4v w1 = {c2[0], c2[1], c3[0], c3[1]};
        u8* d = outQK8 + ((size_t)(bb * NHEADS + h0) * PIX + pp) * 64 + s * 32;
        *(uint4v*)(d) = w0; *(uint4v*)(d + 16) = w1;
      } else {                        // v -> vT[img][pix][32] bf16
        u16* d = (u16*)outT8 + ((size_t)(bb * NHEADS + h0) * PIX + pp) * 32;
        *(uint4v*)(d) = r4[0]; *(uint4v*)(d + 8) = r4[1];
        *(uint4v*)(d + 16) = r4[2]; *(uint4v*)(d + 24) = r4[3];
      }
    } else {  // PROJ -> x1T8 [gp][192] fp8; GELU -> hT8 [gp][768] fp8
      uint2v c0 = bf8_to_fp8x8(r4[0]), c1 = bf8_to_fp8x8(r4[1]);
      uint2v c2 = bf8_to_fp8x8(r4[2]), c3 = bf8_to_fp8x8(r4[3]);
      uint4v w0 = {c0[0], c0[1], c1[0], c1[1]};
      uint4v w1 = {c2[0], c2[1], c3[0], c3[1]};
      int stride = (EPI == MG_PROJ) ? CDIM : 768;
      u8* d = outT8 + (size_t)gp * stride + o0 + half * 32;
      *(uint4v*)(d) = w0; *(uint4v*)(d + 16) = w1;
    }
  }
}

// ------ 7x7 attn conv (MX fp8 K=64) + fused softmax/PV, XCD-swizzled --------
#define VPS 40
#define SMS 65
#define DIV7(t) (((t) * 9363) >> 16)
#define LPOF(t) ((t) + 7 * DIV7(t))

__global__ __launch_bounds__(256, 5) void attn_fused_k(
    const u8* __restrict__ qk8, const u8* __restrict__ wTs8,
    const u16* __restrict__ vT,
    const float* __restrict__ dm_b, const float* __restrict__ rel_bias,
    u8* __restrict__ attnoT8) {
  __shared__ __align__(16) u16 shraw[14216];   // 28432 B -> 5 blocks/CU
  u8* patchB = (u8*)shraw;                     // phase1: 196 x 64B = 12.5 KB
  int bid = (blockIdx.x & 7) * 147 + (blockIdx.x >> 3);
  int img = bid / 49;
  int tile = bid % 49;
  int y0 = (tile / 7) * 8, x0 = (tile % 7) * 8;
  int tid = threadIdx.x;
  const u8* qimg = qk8 + (size_t)img * PIX * 64;
  for (int idx = tid; idx < 784; idx += 256) {
    int lp = idx >> 2, slot = idx & 3;
    int r = lp / 14, c = lp - r * 14;
    int gy = y0 - 3 + r, gx = x0 - 3 + c;
    uint4v val = {0u, 0u, 0u, 0u};
    if ((unsigned)gy < 56u && (unsigned)gx < 56u)
      val = *(const uint4v*)(qimg + (size_t)(gy * 56 + gx) * 64 + slot * 16);
    *(uint4v*)&patchB[lp * 64 + ((slot ^ ((lp >> 1) & 3)) << 4)] = val;
  }
  __syncthreads();

  // T14: issue V-patch global loads now; LDS-write after the MFMA phase.
  const u16* vbase = vT + (size_t)img * PIX * 32;
  uint4v vreg[4];
#pragma unroll
  for (int s = 0; s < 4; s++) {
    int idx = s * 256 + tid;
    uint4v val = {0u, 0u, 0u, 0u};
    if (s < 3 || idx < 784) {
      int g = idx & 3, lp = idx >> 2;
      int r = lp / 14, c = lp - r * 14;
      int gy = y0 - 3 + r, gx = x0 - 3 + c;
      if ((unsigned)gy < 56u && (unsigned)gx < 56u)
        val = *(const uint4v*)(vbase + (size_t)(gy * 56 + gx) * 32 + g * 8);
    }
    vreg[s] = val;
  }

  int lane = tid & 63, wid = tid >> 6;
  int Mtile = wid & 1, Ntile = wid >> 1;
  int n = lane & 31, hi = lane >> 5;
  int py = Ntile * 4 + (n >> 3), px = n & 7;
  int lpb = py * 14 + px;
  f32x16 acc0, acc1;
#pragma unroll
  for (int i = 0; i < 16; i++) { acc0[i] = 0.f; acc1[i] = 0.f; }

  const u8* Aw = wTs8 + Mtile * 2048 + lane * 32;
#pragma unroll
  for (int tap = 0; tap < KWIN; tap++) {
    int lp_ = lpb + LPOF(tap);
    const int4x* ap = (const int4x*)(Aw + tap * 4096);
    int4x alo = ap[0], ahi = ap[1];
    int sw = (lp_ >> 1) & 3;
    int4x blo = *(const int4x*)&patchB[lp_ * 64 + (((2 * hi) ^ sw) << 4)];
    int4x bhi = *(const int4x*)&patchB[lp_ * 64 + (((2 * hi + 1) ^ sw) << 4)];
    int8x a = __builtin_shufflevector(alo, ahi, 0, 1, 2, 3, 4, 5, 6, 7);
    int8x b = __builtin_shufflevector(blo, bhi, 0, 1, 2, 3, 4, 5, 6, 7);
    if (tap & 1)
      acc1 = __builtin_amdgcn_mfma_scale_f32_32x32x64_f8f6f4(
          a, b, acc1, 0, 0, 0, 127, 0, 127);
    else
      acc0 = __builtin_amdgcn_mfma_scale_f32_32x32x64_f8f6f4(
          a, b, acc0, 0, 0, 0, 127, 0, 127);
  }

  // ---- fused tail: logits -> smx[49][SMS], vreg -> vp, softmax, PV ---------
  __syncthreads();
  float* smx = (float*)shraw;            // 49 x 65 x 4 = 12740 B
  u16* vp = shraw + 6376;                // [196 pix][VPS] bf16 (15680 B)
  int head = img % NHEADS;
#pragma unroll
  for (int r = 0; r < 16; r++) {
    int ko = Mtile * 32 + (r & 3) + 8 * (r >> 2) + 4 * hi;
    if (ko < KWIN)
      smx[ko * SMS + Ntile * 32 + n] =
          acc0[r] + acc1[r] + dm_b[ko] + rel_bias[ko * NHEADS + head];
  }
#pragma unroll
  for (int s = 0; s < 4; s++) {
    int idx = s * 256 + tid;
    if (s < 3 || idx < 784) {
      int g = idx & 3, lp = idx >> 2;
      *(uint4v*)&vp[lp * VPS + g * 8] = vreg[s];
    }
  }
  __syncthreads();
  {
    int pxs = tid >> 2, q4 = tid & 3;
    int k0 = q4 * 13;
    int k1 = (q4 == 3) ? KWIN : k0 + 13;
    float m = -1e30f;
    for (int k = k0; k < k1; k++) m = fmaxf(m, smx[k * SMS + pxs]);
    m = fmaxf(m, __shfl_xor(m, 1, 64));
    m = fmaxf(m, __shfl_xor(m, 2, 64));
    float ssum = 0.f;
    for (int k = k0; k < k1; k++) {
      float e = __expf(smx[k * SMS + pxs] - m);
      smx[k * SMS + pxs] = e;
      ssum += e;
    }
    ssum += __shfl_xor(ssum, 1, 64);
    ssum += __shfl_xor(ssum, 2, 64);
    float inv = 1.f / ssum;
    for (int k = k0; k < k1; k++) smx[k * SMS + pxs] *= inv;
  }
  __syncthreads();
  int pxl = tid & 63, co = tid >> 6;
  int pyy = pxl >> 3, pxx = pxl & 7;
  float o8[8] = {0.f, 0.f, 0.f, 0.f, 0.f, 0.f, 0.f, 0.f};
#pragma unroll
  for (int kh = 0; kh < 7; kh++) {
#pragma unroll
    for (int kw = 0; kw < 7; kw++) {
      float p = smx[(kh * 7 + kw) * SMS + pxl];
      bf16x8 v = *(const bf16x8*)&vp[((pyy + kh) * 14 + pxx + kw) * VPS + co * 8];
#pragma unroll
      for (int j = 0; j < 8; j++) o8[j] += p * (float)v[j];
    }
  }
  int gp = (y0 + pyy) * 56 + x0 + pxx;
  int b = img / NHEADS;
  uint2v w = f32x8_to_fp8(o8);
  *(uint2v*)(attnoT8 + ((size_t)b * PIX + gp) * CDIM + head * 32 + co * 8) = w;
}

// ---------------- launch ----------------------------------------------------
extern "C" void kernel_launch(void* const* d_in, const int* in_sizes, int n_in,
                              void* d_out, int out_size, void* d_ws, size_t ws_size,
                              hipStream_t stream) {
  const float* x        = (const float*)d_in[0];
  const float* bn_gamma = (const float*)d_in[1];
  const float* bn_beta  = (const float*)d_in[2];
  const float* qkv_w    = (const float*)d_in[3];
  const float* qkv_b    = (const float*)d_in[4];
  const float* dm_w     = (const float*)d_in[5];
  const float* dm_b     = (const float*)d_in[6];
  const float* rel_bias = (const float*)d_in[7];
  const float* proj_w   = (const float*)d_in[8];
  const float* proj_b   = (const float*)d_in[9];
  const float* c1_w     = (const float*)d_in[10];
  const float* c1_b     = (const float*)d_in[11];
  const float* c2_w     = (const float*)d_in[12];
  const float* c2_b     = (const float*)d_in[13];
  float* out = (float*)d_out;
  float* ws  = (float*)d_ws;

  float* stats    = ws;                            // 384 f
  float* b_eff    = stats + 384;                   // 576 f
  u8*    pk_qkv8  = (u8*)(b_eff + 576);            // 110592 B
  u8*    pk_proj8 = pk_qkv8 + 110592;              // 36864 B
  u8*    pk_c18   = pk_proj8 + 36864;              // 147456 B
  u8*    pk_c28   = pk_c18 + 147456;               // 147456 B
  u8*    wTs8     = pk_c28 + 147456;               // 200704 B
  u8*    xT8      = wTs8 + 200704;                 // 2408448 B
  u8*    qk8      = xT8 + 2408448;                 // 4816896 B
  u16*   vT       = (u16*)(qk8 + 4816896);         // 2408448 u16
  u8*    attnoT8  = (u8*)(vT + 2408448);           // 2408448 B
  u16*   x1b      = (u16*)(attnoT8 + 2408448);     // 2408448 u16 (bf16 x1)
  u8*    x1T8     = (u8*)(x1b + 2408448);          // 2408448 B
  u8*    hT8      = x1T8 + 2408448;                // 9633792 B

  bn_stats_k<<<CDIM, 256, 0, stream>>>(x, stats);
  prep5_k<<<2394, 256, 0, stream>>>(qkv_w, qkv_b, bn_gamma, bn_beta, stats,
                                    pk_qkv8, b_eff, dm_w, wTs8,
                                    proj_w, pk_proj8, c1_w, pk_c18,
                                    c2_w, pk_c28, x, xT8);

  mgemm8_k<MG_QKV><<<dim3(98, 9), 256, 0, stream>>>(
      xT8, pk_qkv8, b_eff, nullptr, (u8*)vT, nullptr, qk8, nullptr, 192);
  attn_fused_k<<<NIMG * 49, 256, 0, stream>>>(qk8, wTs8, vT, dm_b, rel_bias, attnoT8);
  mgemm8_k<MG_PROJ><<<dim3(98, 3), 256, 0, stream>>>(
      attnoT8, pk_proj8, proj_b, nullptr, x1T8, x1b, nullptr, x, 192);
  mgemm8_k<MG_GELU><<<dim3(98, 12), 256, 0, stream>>>(
      x1T8, pk_c18, c1_b, nullptr, hT8, nullptr, nullptr, nullptr, 192);
  mgemm8_k<MG_C2><<<dim3(98, 3), 256, 0, stream>>>(
      hT8, pk_c28, c2_b, out, nullptr, x1b, nullptr, nullptr, 768);
}